// Round 10
// baseline (313.986 us; speedup 1.0000x reference)
//
#include <hip/hip_runtime.h>

typedef __bf16 bf16;
typedef __bf16 bf16x4 __attribute__((ext_vector_type(4)));
typedef __bf16 bf16x8 __attribute__((ext_vector_type(8)));
typedef float f32x4 __attribute__((ext_vector_type(4)));

#define MFMA_16x16x32(a, b, c) __builtin_amdgcn_mfma_f32_16x16x32_bf16((a), (b), (c), 0, 0, 0)

#define B_ 8
#define N_ 1024
#define C_ 768
#define H_ 12
#define HD_ 64
#define KDIM 768

__device__ __forceinline__ void gload_lds16(const void* g, void* l) {
  __builtin_amdgcn_global_load_lds(
      (const __attribute__((address_space(1))) void*)g,
      (__attribute__((address_space(3))) void*)l, 16, 0, 0);
}

// ---------------------------------------------------------------------------
// mask dtype detection (robust to int8/int32/int64 storage)
// ---------------------------------------------------------------------------
__global__ __launch_bounds__(256) void detect_mask_kernel(const unsigned* __restrict__ m32,
                                                          int* __restrict__ flags) {
  const int i = blockIdx.x * 256 + threadIdx.x;
  if (i < 2048) {
    const unsigned v = m32[i];
    if (v > 1u) atomicOr(&flags[0], 1);
    if ((i & 1) && v != 0u) atomicOr(&flags[1], 1);
  }
}

// ---------------------------------------------------------------------------
// cvt: f32 -> bf16 for x, w_qkv, w_proj; bias[b*N+n] = mask ? -1e30 : log(size)
// ---------------------------------------------------------------------------
__global__ __launch_bounds__(256) void cvt_kernel(const float* __restrict__ x,
                                                  const float* __restrict__ wq,
                                                  const float* __restrict__ wp,
                                                  const float* __restrict__ size_in,
                                                  const void* __restrict__ mask_raw,
                                                  const int* __restrict__ flags,
                                                  bf16* __restrict__ xb,
                                                  bf16* __restrict__ wqb,
                                                  bf16* __restrict__ wpb,
                                                  float* __restrict__ biasb) {
  const int i = blockIdx.x * 256 + threadIdx.x;  // grid covers 6291456/4
  {
    const float4 v = ((const float4*)x)[i];
    bf16x4 o = {(bf16)v.x, (bf16)v.y, (bf16)v.z, (bf16)v.w};
    ((bf16x4*)xb)[i] = o;
  }
  if (i < 442368) {  // 2304*768/4
    const float4 v = ((const float4*)wq)[i];
    bf16x4 o = {(bf16)v.x, (bf16)v.y, (bf16)v.z, (bf16)v.w};
    ((bf16x4*)wqb)[i] = o;
  }
  if (i < 147456) {  // 768*768/4
    const float4 v = ((const float4*)wp)[i];
    bf16x4 o = {(bf16)v.x, (bf16)v.y, (bf16)v.z, (bf16)v.w};
    ((bf16x4*)wpb)[i] = o;
  }
  if (i < B_ * N_) {
    int mv;
    if (flags[0]) {
      mv = (int)((const unsigned char*)mask_raw)[i];
    } else if (flags[1]) {
      mv = ((const int*)mask_raw)[i];
    } else {  // int64
      const unsigned* m32 = (const unsigned*)mask_raw;
      mv = (int)(m32[2 * i] | m32[2 * i + 1]);
    }
    biasb[i] = mv ? -1e30f : logf(size_in[i]);
  }
}

// ---------------------------------------------------------------------------
// GEMM (NT): out[m][o] = sum_k A[m][k] * W[o][k].  M=8192, K=768.
// MODE 0: A linear [m][768]; scatter epilogue into q/k/vt
// MODE 1: A in [b][h][n][64] layout (attnw2); f32 epilogue outf = acc + bias
// ---------------------------------------------------------------------------
template <int MODE>
__global__ __launch_bounds__(256) void gemm_bt(const bf16* __restrict__ A,
                                               const bf16* __restrict__ W,
                                               const float* __restrict__ bias,
                                               bf16* __restrict__ out0,
                                               bf16* __restrict__ out1,
                                               bf16* __restrict__ out2,
                                               float* __restrict__ outf) {
  __shared__ bf16 As[128 * 64];
  __shared__ bf16 Bs[128 * 64];
  const int bid = blockIdx.x;
  const int mt = bid % 64;
  const int nt = bid / 64;
  const int t = threadIdx.x;
  const int lane = t & 63, w = t >> 6;
  const int wm = w >> 1, wn = w & 1;
  const int l15 = lane & 15, lg = lane >> 4;

  f32x4 acc[4][4] = {};

  const int srow = t >> 3;
  const int skel = (t & 7) * 8;
  const bf16* Ag = A + (size_t)(mt * 128) * KDIM;
  const bf16* Bg = W + (size_t)(nt * 128) * KDIM;
  const int bA = mt >> 3;              // MODE 1: batch of this M-tile
  const int nbase = (mt & 7) * 128;    // MODE 1: n-base of this M-tile

  for (int kt = 0; kt < KDIM; kt += 64) {
#pragma unroll
    for (int c = 0; c < 4; ++c) {
      const bf16* aSrc;
      if (MODE == 0)
        aSrc = Ag + (size_t)(c * 32 + srow) * KDIM + kt + skel;
      else  // [b][h][n][64]: k-tile kt lies entirely in head h = kt/64
        aSrc = A + (((size_t)(bA * 12 + (kt >> 6)) * 1024) + nbase + c * 32 + srow) * 64 + skel;
      gload_lds16(aSrc, (char*)As + c * 4096 + w * 1024);
      gload_lds16(Bg + (size_t)(c * 32 + srow) * KDIM + kt + skel,
                  (char*)Bs + c * 4096 + w * 1024);
    }
    __syncthreads();
#pragma unroll
    for (int ks = 0; ks < 2; ++ks) {
      bf16x8 af[4], bfr[4];
#pragma unroll
      for (int i = 0; i < 4; ++i)
        af[i] = *(const bf16x8*)(As + (wm * 64 + i * 16 + l15) * 64 + ks * 32 + lg * 8);
#pragma unroll
      for (int i = 0; i < 4; ++i)
        bfr[i] = *(const bf16x8*)(Bs + (wn * 64 + i * 16 + l15) * 64 + ks * 32 + lg * 8);
#pragma unroll
      for (int i = 0; i < 4; ++i)
#pragma unroll
        for (int j = 0; j < 4; ++j)
          acc[i][j] = MFMA_16x16x32(af[i], bfr[j], acc[i][j]);
    }
    __syncthreads();
  }

  if (MODE == 0) {
    const int which = (nt * 128) / 768;  // 768 = 6*128, tiles never straddle
#pragma unroll
    for (int i = 0; i < 4; ++i)
#pragma unroll
      for (int j = 0; j < 4; ++j)
#pragma unroll
        for (int r = 0; r < 4; ++r) {
          const int m = mt * 128 + wm * 64 + i * 16 + lg * 4 + r;
          const int o = nt * 128 + wn * 64 + j * 16 + l15;
          const int b = m >> 10, n = m & 1023;
          const int f = o - which * 768;
          const int h = f >> 6, hd = f & 63;
          const bf16 bv = (bf16)acc[i][j][r];
          if (which == 0)
            out0[(((size_t)(b * 12 + h)) * 1024 + n) * 64 + hd] = bv;
          else if (which == 1)
            out1[(((size_t)(b * 12 + h)) * 1024 + n) * 64 + hd] = bv;
          else
            out2[(((size_t)(b * 12 + h)) * 64 + hd) * 1024 + n] = bv;
        }
  } else {
#pragma unroll
    for (int i = 0; i < 4; ++i)
#pragma unroll
      for (int j = 0; j < 4; ++j) {
        const int o = nt * 128 + wn * 64 + j * 16 + l15;
        const float bv = bias[o];
#pragma unroll
        for (int r = 0; r < 4; ++r) {
          const int m = mt * 128 + wm * 64 + i * 16 + lg * 4 + r;
          outf[(size_t)m * 768 + o] = acc[i][j][r] + bv;
        }
      }
  }
}

// ---------------------------------------------------------------------------
// k_mean (f32 out): kmean[b,n,hd] = mean_h k[b,h,n,hd]
// ---------------------------------------------------------------------------
__global__ __launch_bounds__(256) void kmean_kernel(const bf16* __restrict__ kbuf,
                                                    float* __restrict__ kmean) {
  const int i = blockIdx.x * 256 + threadIdx.x;
  if (i >= B_ * N_ * HD_) return;
  const int hd = i & 63;
  const int n = (i >> 6) & 1023;
  const int b = i >> 16;
  float s = 0.f;
#pragma unroll
  for (int h = 0; h < 12; ++h)
    s += (float)kbuf[(((size_t)(b * 12 + h)) * 1024 + n) * 64 + hd];
  kmean[i] = s * (1.0f / 12.0f);
}

// ---------------------------------------------------------------------------
// MFMA flash attention (R8-validated compute). Block = 4 waves (64 q-rows),
// KBLK = 64, double-buffered LDS K/V, swapped-operand QK^T, lane-local
// softmax. Changes vs R8: (1) grid order id = qt*96 + bh (XCD=bh%8 under %8
// round-robin -> K/V L2 pinning attempt; FETCH counter disambiguates);
// (2) output written to attnw2[b][h][n][64] -> each block stores one fully
// CONTIGUOUS 8KB region (write-amp 1x under any XCD mapping).
// ---------------------------------------------------------------------------
__global__ __launch_bounds__(256, 5) void attn_mfma(const bf16* __restrict__ qbuf,
                                                    const bf16* __restrict__ kbuf,
                                                    const bf16* __restrict__ vtbuf,
                                                    const float* __restrict__ biasb,
                                                    bf16* __restrict__ outws) {
  __shared__ bf16 Ks[2][4096];  // [64 rows][8 slots of 8 elems], swizzled
  __shared__ bf16 Vs[2][4096];
  const int id = blockIdx.x;
  const int bh = id % 96;
  const int qt = id / 96;           // 0..15
  const int b = bh / 12;
  const int t = threadIdx.x, lane = t & 63, w = t >> 6;
  const int l15 = lane & 15, lg = lane >> 4;
  const int qbase = qt * 64 + w * 16;

  const bf16* Q = qbuf + ((size_t)bh * 1024 + qbase) * 64;
  const bf16* Kp = kbuf + (size_t)bh * 65536;
  const bf16* Vt = vtbuf + (size_t)bh * 65536;
  const float* bias = biasb + b * 1024;

  // Q as B-operand: col=l15 (q-row), k-slots lg*8+e = d
  const bf16x8 qb0 = *(const bf16x8*)(Q + l15 * 64 + lg * 8);
  const bf16x8 qb1 = *(const bf16x8*)(Q + l15 * 64 + 32 + lg * 8);

  // staging geometry (R8): thread covers LDS 16B slot (row=t>>3 [+32], sl=t&7);
  // phys slot sl holds logical slot sl^(row&7); K row j holds key pi(j).
  const int srow = t >> 3;                 // 0..31
  const int dsl = (t & 7) ^ (srow & 7);    // logical slot fetched
  const int pi0 = 4 * ((srow >> 4) & 1) + 8 * ((srow >> 2) & 3) + (srow & 3);
  const bf16* srcK0 = Kp + pi0 * 64 + dsl * 8;          // rows j = srow
  const bf16* srcK1 = Kp + (32 + pi0) * 64 + dsl * 8;   // rows j = 32+srow
  const bf16* srcV0 = Vt + (size_t)srow * 1024 + dsl * 8;
  const bf16* srcV1 = Vt + (size_t)(32 + srow) * 1024 + dsl * 8;
  char* const ldsK0 = (char*)&Ks[0][0] + w * 1024;
  char* const ldsK1 = (char*)&Ks[1][0] + w * 1024;
  char* const ldsV0 = (char*)&Vs[0][0] + w * 1024;
  char* const ldsV1 = (char*)&Vs[1][0] + w * 1024;

  // prologue: stage tile 0 into buf 0
  gload_lds16(srcK0, ldsK0);
  gload_lds16(srcK1, ldsK0 + 4096);  // rows 32..63 at +4KB
  gload_lds16(srcV0, ldsV0);
  gload_lds16(srcV1, ldsV0 + 4096);
  __syncthreads();

  const int bb0 = 8 * lg;        // bias quad base (D-row=lg*4+j)
  const int swz = l15 & 7;

  f32x4 oacc[4] = {};
  float m = -1e30f, l = 0.f;

  for (int kt = 0; kt < 16; ++kt) {
    const int cur = kt & 1;
    const int kb = kt * 64;
    if (kt < 15) {  // stage next tile into the other buffer
      const size_t ko = (size_t)(kb + 64) * 64;
      char* const nK = cur ? ldsK0 : ldsK1;
      char* const nV = cur ? ldsV0 : ldsV1;
      gload_lds16(srcK0 + ko, nK);
      gload_lds16(srcK1 + ko, nK + 4096);
      gload_lds16(srcV0 + (kb + 64), nV);
      gload_lds16(srcV1 + (kb + 64), nV + 4096);
    }

    const bf16* LK = Ks[cur];
    const bf16* LV = Vs[cur];
    float sv[4][4];
#pragma unroll
    for (int f = 0; f < 4; ++f) {
      const int cf = 32 * (f >> 1) + 4 * (f & 1);
      const bf16* kj = LK + (f * 16 + l15) * 64;
      const bf16x8 ka0 = *(const bf16x8*)(kj + (lg ^ swz) * 8);
      const bf16x8 ka1 = *(const bf16x8*)(kj + ((lg + 4) ^ swz) * 8);
      f32x4 z = {};
      z = MFMA_16x16x32(ka0, qb0, z);
      z = MFMA_16x16x32(ka1, qb1, z);
      const float4 bi = *(const float4*)(bias + kb + cf + bb0);
      sv[f][0] = z[0] * 0.125f + bi.x;
      sv[f][1] = z[1] * 0.125f + bi.y;
      sv[f][2] = z[2] * 0.125f + bi.z;
      sv[f][3] = z[3] * 0.125f + bi.w;
    }
    // max over 64 keys for this lane's q=l15: 15 local + 2 shuffles
    float mx = sv[0][0];
#pragma unroll
    for (int f = 0; f < 4; ++f)
#pragma unroll
      for (int j = 0; j < 4; ++j) mx = fmaxf(mx, sv[f][j]);
    mx = fmaxf(mx, __shfl_xor(mx, 16, 64));
    mx = fmaxf(mx, __shfl_xor(mx, 32, 64));
    const float mn = fmaxf(m, mx);
    const float resc = __expf(m - mn);
    m = mn;

    float rs = 0.f;
    bf16x8 pa0, pa1;
#pragma unroll
    for (int f = 0; f < 4; ++f)
#pragma unroll
      for (int j = 0; j < 4; ++j) {
        const float p = __expf(sv[f][j] - mn);
        rs += p;
        const bf16 pb = (bf16)p;
        if (f == 0) pa0[j] = pb;
        else if (f == 1) pa0[4 + j] = pb;
        else if (f == 2) pa1[j] = pb;
        else pa1[4 + j] = pb;
      }
    rs += __shfl_xor(rs, 16, 64);
    rs += __shfl_xor(rs, 32, 64);
    l = l * resc + rs;

#pragma unroll
    for (int df = 0; df < 4; ++df) {
      f32x4 t4 = oacc[df];
#pragma unroll
      for (int j = 0; j < 4; ++j) t4[j] *= resc;
      const bf16* vj = LV + (df * 16 + l15) * 64;
      const bf16x8 va0 = *(const bf16x8*)(vj + (lg ^ swz) * 8);
      const bf16x8 va1 = *(const bf16x8*)(vj + ((lg + 4) ^ swz) * 8);
      t4 = MFMA_16x16x32(va0, pa0, t4);
      t4 = MFMA_16x16x32(va1, pa1, t4);
      oacc[df] = t4;
    }
    __syncthreads();  // drains vmcnt (stage t+1 done); frees buf[cur]
  }

  // contiguous store: attnw2[b][h][n][64], block region = 64 rows x 128B
  const float inv = 1.0f / l;
  bf16* outp = outws + ((size_t)bh * 1024 + qbase + l15) * 64;
#pragma unroll
  for (int df = 0; df < 4; ++df) {
    bf16x4 ov = {(bf16)(oacc[df][0] * inv), (bf16)(oacc[df][1] * inv),
                 (bf16)(oacc[df][2] * inv), (bf16)(oacc[df][3] * inv)};
    *(bf16x4*)(outp + df * 16 + lg * 4) = ov;
  }
}

// ---------------------------------------------------------------------------
extern "C" void kernel_launch(void* const* d_in, const int* in_sizes, int n_in,
                              void* d_out, int out_size, void* d_ws, size_t ws_size,
                              hipStream_t stream) {
  const float* x       = (const float*)d_in[0];
  const float* size_in = (const float*)d_in[1];
  const void*  mask    = d_in[2];
  const float* w_qkv   = (const float*)d_in[3];
  const float* w_proj  = (const float*)d_in[4];
  const float* b_proj  = (const float*)d_in[5];
  float* out = (float*)d_out;   // f32 outputs per reference dtype

  if (n_in < 6 ||
      in_sizes[0] != 6291456 || in_sizes[1] != 8192 || in_sizes[2] != 8192 ||
      in_sizes[3] != 1769472 || in_sizes[4] != 589824 || in_sizes[5] != 768)
    return;

  const size_t QS = (size_t)B_ * H_ * N_ * HD_;  // 6291456 elems
  if (ws_size < 55083024) return;

  bf16* xb    = (bf16*)d_ws;       // dead after gemm<0>; reused as attnw2
  bf16* qbuf  = xb + QS;
  bf16* kbuf  = qbuf + QS;
  bf16* vtbuf = kbuf + QS;
  bf16* wqb   = vtbuf + QS;        // 1769472 elems
  bf16* wpb   = wqb + 1769472;     // 589824 elems
  float* biasb = (float*)(wpb + 589824);
  int* flags = (int*)(biasb + 8192);
  bf16* attnw2 = xb;               // [b][h][n][64]

  hipMemsetAsync(flags, 0, 8, stream);
  detect_mask_kernel<<<8, 256, 0, stream>>>((const unsigned*)mask, flags);
  cvt_kernel<<<6144, 256, 0, stream>>>(x, w_qkv, w_proj, size_in, mask, flags,
                                       xb, wqb, wpb, biasb);
  gemm_bt<0><<<64 * 18, 256, 0, stream>>>(xb, wqb, nullptr, qbuf, kbuf, vtbuf, nullptr);
  kmean_kernel<<<2048, 256, 0, stream>>>(kbuf, out + (size_t)B_ * N_ * C_);
  attn_mfma<<<1536, 256, 0, stream>>>(qbuf, kbuf, vtbuf, biasb, attnw2);
  gemm_bt<1><<<64 * 6, 256, 0, stream>>>(attnw2, wpb, b_proj, nullptr, nullptr, nullptr, out);
}

// Round 11
// 218.821 us; speedup vs baseline: 1.4349x; 1.4349x over previous
//
#include <hip/hip_runtime.h>

typedef __bf16 bf16;
typedef __bf16 bf16x4 __attribute__((ext_vector_type(4)));
typedef __bf16 bf16x8 __attribute__((ext_vector_type(8)));
typedef float f32x4 __attribute__((ext_vector_type(4)));

#define MFMA_16x16x32(a, b, c) __builtin_amdgcn_mfma_f32_16x16x32_bf16((a), (b), (c), 0, 0, 0)

#define B_ 8
#define N_ 1024
#define C_ 768
#define H_ 12
#define HD_ 64
#define KDIM 768

__device__ __forceinline__ void gload_lds16(const void* g, void* l) {
  __builtin_amdgcn_global_load_lds(
      (const __attribute__((address_space(1))) void*)g,
      (__attribute__((address_space(3))) void*)l, 16, 0, 0);
}

// ---------------------------------------------------------------------------
// mask dtype detection (robust to int8/int32/int64 storage)
// ---------------------------------------------------------------------------
__global__ __launch_bounds__(256) void detect_mask_kernel(const unsigned* __restrict__ m32,
                                                          int* __restrict__ flags) {
  const int i = blockIdx.x * 256 + threadIdx.x;
  if (i < 2048) {
    const unsigned v = m32[i];
    if (v > 1u) atomicOr(&flags[0], 1);
    if ((i & 1) && v != 0u) atomicOr(&flags[1], 1);
  }
}

// ---------------------------------------------------------------------------
// cvt: f32 -> bf16 for x, w_qkv, w_proj; bias[b*N+n] = mask ? -1e30 : log(size)
// ---------------------------------------------------------------------------
__global__ __launch_bounds__(256) void cvt_kernel(const float* __restrict__ x,
                                                  const float* __restrict__ wq,
                                                  const float* __restrict__ wp,
                                                  const float* __restrict__ size_in,
                                                  const void* __restrict__ mask_raw,
                                                  const int* __restrict__ flags,
                                                  bf16* __restrict__ xb,
                                                  bf16* __restrict__ wqb,
                                                  bf16* __restrict__ wpb,
                                                  float* __restrict__ biasb) {
  const int i = blockIdx.x * 256 + threadIdx.x;  // grid covers 6291456/4
  {
    const float4 v = ((const float4*)x)[i];
    bf16x4 o = {(bf16)v.x, (bf16)v.y, (bf16)v.z, (bf16)v.w};
    ((bf16x4*)xb)[i] = o;
  }
  if (i < 442368) {  // 2304*768/4
    const float4 v = ((const float4*)wq)[i];
    bf16x4 o = {(bf16)v.x, (bf16)v.y, (bf16)v.z, (bf16)v.w};
    ((bf16x4*)wqb)[i] = o;
  }
  if (i < 147456) {  // 768*768/4
    const float4 v = ((const float4*)wp)[i];
    bf16x4 o = {(bf16)v.x, (bf16)v.y, (bf16)v.z, (bf16)v.w};
    ((bf16x4*)wpb)[i] = o;
  }
  if (i < B_ * N_) {
    int mv;
    if (flags[0]) {
      mv = (int)((const unsigned char*)mask_raw)[i];
    } else if (flags[1]) {
      mv = ((const int*)mask_raw)[i];
    } else {  // int64
      const unsigned* m32 = (const unsigned*)mask_raw;
      mv = (int)(m32[2 * i] | m32[2 * i + 1]);
    }
    biasb[i] = mv ? -1e30f : logf(size_in[i]);
  }
}

// ---------------------------------------------------------------------------
// GEMM (NT): out[m][o] = sum_k A[m][k] * W[o][k].  M=8192, K=768.
// MODE 0: scatter epilogue into q[B,H,N,64], k[B,H,N,64], vt[B,H,64,N]
// MODE 1: f32 epilogue outf[m*768+o] = acc + bias[o]
// ---------------------------------------------------------------------------
template <int MODE>
__global__ __launch_bounds__(256) void gemm_bt(const bf16* __restrict__ A,
                                               const bf16* __restrict__ W,
                                               const float* __restrict__ bias,
                                               bf16* __restrict__ out0,
                                               bf16* __restrict__ out1,
                                               bf16* __restrict__ out2,
                                               float* __restrict__ outf) {
  __shared__ bf16 As[128 * 64];
  __shared__ bf16 Bs[128 * 64];
  const int bid = blockIdx.x;
  const int mt = bid % 64;
  const int nt = bid / 64;
  const int t = threadIdx.x;
  const int lane = t & 63, w = t >> 6;
  const int wm = w >> 1, wn = w & 1;
  const int l15 = lane & 15, lg = lane >> 4;

  f32x4 acc[4][4] = {};

  const int srow = t >> 3;
  const int skel = (t & 7) * 8;
  const bf16* Ag = A + (size_t)(mt * 128) * KDIM;
  const bf16* Bg = W + (size_t)(nt * 128) * KDIM;

  for (int kt = 0; kt < KDIM; kt += 64) {
#pragma unroll
    for (int c = 0; c < 4; ++c) {
      gload_lds16(Ag + (size_t)(c * 32 + srow) * KDIM + kt + skel,
                  (char*)As + c * 4096 + w * 1024);
      gload_lds16(Bg + (size_t)(c * 32 + srow) * KDIM + kt + skel,
                  (char*)Bs + c * 4096 + w * 1024);
    }
    __syncthreads();
#pragma unroll
    for (int ks = 0; ks < 2; ++ks) {
      bf16x8 af[4], bfr[4];
#pragma unroll
      for (int i = 0; i < 4; ++i)
        af[i] = *(const bf16x8*)(As + (wm * 64 + i * 16 + l15) * 64 + ks * 32 + lg * 8);
#pragma unroll
      for (int i = 0; i < 4; ++i)
        bfr[i] = *(const bf16x8*)(Bs + (wn * 64 + i * 16 + l15) * 64 + ks * 32 + lg * 8);
#pragma unroll
      for (int i = 0; i < 4; ++i)
#pragma unroll
        for (int j = 0; j < 4; ++j)
          acc[i][j] = MFMA_16x16x32(af[i], bfr[j], acc[i][j]);
    }
    __syncthreads();
  }

  if (MODE == 0) {
    const int which = (nt * 128) / 768;  // 768 = 6*128, tiles never straddle
#pragma unroll
    for (int i = 0; i < 4; ++i)
#pragma unroll
      for (int j = 0; j < 4; ++j)
#pragma unroll
        for (int r = 0; r < 4; ++r) {
          const int m = mt * 128 + wm * 64 + i * 16 + lg * 4 + r;
          const int o = nt * 128 + wn * 64 + j * 16 + l15;
          const int b = m >> 10, n = m & 1023;
          const int f = o - which * 768;
          const int h = f >> 6, hd = f & 63;
          const bf16 bv = (bf16)acc[i][j][r];
          if (which == 0)
            out0[(((size_t)(b * 12 + h)) * 1024 + n) * 64 + hd] = bv;
          else if (which == 1)
            out1[(((size_t)(b * 12 + h)) * 1024 + n) * 64 + hd] = bv;
          else
            out2[(((size_t)(b * 12 + h)) * 64 + hd) * 1024 + n] = bv;
        }
  } else {
#pragma unroll
    for (int i = 0; i < 4; ++i)
#pragma unroll
      for (int j = 0; j < 4; ++j) {
        const int o = nt * 128 + wn * 64 + j * 16 + l15;
        const float bv = bias[o];
#pragma unroll
        for (int r = 0; r < 4; ++r) {
          const int m = mt * 128 + wm * 64 + i * 16 + lg * 4 + r;
          outf[(size_t)m * 768 + o] = acc[i][j][r] + bv;
        }
      }
  }
}

// ---------------------------------------------------------------------------
// k_mean (f32 out): kmean[b,n,hd] = mean_h k[b,h,n,hd]
// ---------------------------------------------------------------------------
__global__ __launch_bounds__(256) void kmean_kernel(const bf16* __restrict__ kbuf,
                                                    float* __restrict__ kmean) {
  const int i = blockIdx.x * 256 + threadIdx.x;
  if (i >= B_ * N_ * HD_) return;
  const int hd = i & 63;
  const int n = (i >> 6) & 1023;
  const int b = i >> 16;
  float s = 0.f;
#pragma unroll
  for (int h = 0; h < 12; ++h)
    s += (float)kbuf[(((size_t)(b * 12 + h)) * 1024 + n) * 64 + hd];
  kmean[i] = s * (1.0f / 12.0f);
}

// ---------------------------------------------------------------------------
// MFMA flash attention (R8 structure, 2 q-tiles/block). Block = 4 waves,
// 128 q-rows (two 64-row tiles sharing each staged K/V tile), KBLK = 64,
// grid = bh*8 + qt (consecutive blocks share a bh -> temporal K/V locality;
// the empirically-best R8 ordering). Double-buffered LDS K/V via
// global_load_lds with pre-swizzled source; swapped-operand QK^T; lane-local
// softmax (2 shuffles); P never leaves the lane. Per barrier interval:
// 32 MFMA vs 4 staging loads -> staging latency amortized 2x vs R8.
// ---------------------------------------------------------------------------
__global__ __launch_bounds__(256, 5) void attn_mfma(const bf16* __restrict__ qbuf,
                                                    const bf16* __restrict__ kbuf,
                                                    const bf16* __restrict__ vtbuf,
                                                    const float* __restrict__ biasb,
                                                    bf16* __restrict__ outws) {
  __shared__ bf16 Ks[2][4096];  // [64 rows][8 slots of 8 elems], swizzled
  __shared__ bf16 Vs[2][4096];
  const int id = blockIdx.x;
  const int qt = id & 7;
  const int bh = id >> 3;
  const int b = bh / 12, h = bh % 12;
  const int t = threadIdx.x, lane = t & 63, w = t >> 6;
  const int l15 = lane & 15, lg = lane >> 4;
  const int qbase = qt * 128 + w * 16;   // tile0 rows; tile1 = qbase + 64

  const bf16* Q = qbuf + ((size_t)bh * 1024 + qbase) * 64;
  const bf16* Kp = kbuf + (size_t)bh * 65536;
  const bf16* Vt = vtbuf + (size_t)bh * 65536;
  const float* bias = biasb + b * 1024;

  // Q as B-operand: col=l15 (q-row), k-slots lg*8+e = d
  const bf16x8 qb0 = *(const bf16x8*)(Q + l15 * 64 + lg * 8);
  const bf16x8 qb1 = *(const bf16x8*)(Q + l15 * 64 + 32 + lg * 8);
  const bf16x8 qc0 = *(const bf16x8*)(Q + (64 + l15) * 64 + lg * 8);
  const bf16x8 qc1 = *(const bf16x8*)(Q + (64 + l15) * 64 + 32 + lg * 8);

  // staging geometry (R8): thread covers LDS 16B slot (row=t>>3 [+32], sl=t&7);
  // phys slot sl holds logical slot sl^(row&7); K row j holds key pi(j).
  const int srow = t >> 3;                 // 0..31
  const int dsl = (t & 7) ^ (srow & 7);    // logical slot fetched
  const int pi0 = 4 * ((srow >> 4) & 1) + 8 * ((srow >> 2) & 3) + (srow & 3);
  const bf16* srcK0 = Kp + pi0 * 64 + dsl * 8;          // rows j = srow
  const bf16* srcK1 = Kp + (32 + pi0) * 64 + dsl * 8;   // rows j = 32+srow
  const bf16* srcV0 = Vt + (size_t)srow * 1024 + dsl * 8;
  const bf16* srcV1 = Vt + (size_t)(32 + srow) * 1024 + dsl * 8;
  char* const ldsK0 = (char*)&Ks[0][0] + w * 1024;
  char* const ldsK1 = (char*)&Ks[1][0] + w * 1024;
  char* const ldsV0 = (char*)&Vs[0][0] + w * 1024;
  char* const ldsV1 = (char*)&Vs[1][0] + w * 1024;

  // prologue: stage tile 0 into buf 0
  gload_lds16(srcK0, ldsK0);
  gload_lds16(srcK1, ldsK0 + 4096);  // rows 32..63 at +4KB
  gload_lds16(srcV0, ldsV0);
  gload_lds16(srcV1, ldsV0 + 4096);
  __syncthreads();

  const int bb0 = 8 * lg;        // bias quad base (D-row=lg*4+j)
  const int swz = l15 & 7;

  f32x4 oacc[4] = {}, oacc2[4] = {};
  float m = -1e30f, l = 0.f;
  float m2 = -1e30f, l2 = 0.f;

  for (int kt = 0; kt < 16; ++kt) {
    const int cur = kt & 1;
    const int kb = kt * 64;
    if (kt < 15) {  // stage next tile into the other buffer
      const size_t ko = (size_t)(kb + 64) * 64;
      char* const nK = cur ? ldsK0 : ldsK1;
      char* const nV = cur ? ldsV0 : ldsV1;
      gload_lds16(srcK0 + ko, nK);
      gload_lds16(srcK1 + ko, nK + 4096);
      gload_lds16(srcV0 + (kb + 64), nV);
      gload_lds16(srcV1 + (kb + 64), nV + 4096);
    }

    const bf16* LK = Ks[cur];
    const bf16* LV = Vs[cur];
    float sv[4][4], sw[4][4];
#pragma unroll
    for (int f = 0; f < 4; ++f) {
      const int cf = 32 * (f >> 1) + 4 * (f & 1);
      const bf16* kj = LK + (f * 16 + l15) * 64;
      const bf16x8 ka0 = *(const bf16x8*)(kj + (lg ^ swz) * 8);
      const bf16x8 ka1 = *(const bf16x8*)(kj + ((lg + 4) ^ swz) * 8);
      f32x4 z = {}, y = {};
      z = MFMA_16x16x32(ka0, qb0, z);
      y = MFMA_16x16x32(ka0, qc0, y);
      z = MFMA_16x16x32(ka1, qb1, z);
      y = MFMA_16x16x32(ka1, qc1, y);
      const float4 bi = *(const float4*)(bias + kb + cf + bb0);
      sv[f][0] = z[0] * 0.125f + bi.x;
      sv[f][1] = z[1] * 0.125f + bi.y;
      sv[f][2] = z[2] * 0.125f + bi.z;
      sv[f][3] = z[3] * 0.125f + bi.w;
      sw[f][0] = y[0] * 0.125f + bi.x;
      sw[f][1] = y[1] * 0.125f + bi.y;
      sw[f][2] = y[2] * 0.125f + bi.z;
      sw[f][3] = y[3] * 0.125f + bi.w;
    }
    // per-tile max over 64 keys: 15 local + 2 shuffles each
    float mx = sv[0][0], mx2 = sw[0][0];
#pragma unroll
    for (int f = 0; f < 4; ++f)
#pragma unroll
      for (int j = 0; j < 4; ++j) {
        mx = fmaxf(mx, sv[f][j]);
        mx2 = fmaxf(mx2, sw[f][j]);
      }
    mx = fmaxf(mx, __shfl_xor(mx, 16, 64));
    mx = fmaxf(mx, __shfl_xor(mx, 32, 64));
    mx2 = fmaxf(mx2, __shfl_xor(mx2, 16, 64));
    mx2 = fmaxf(mx2, __shfl_xor(mx2, 32, 64));
    const float mn = fmaxf(m, mx);
    const float mn2 = fmaxf(m2, mx2);
    const float resc = __expf(m - mn);
    const float resc2 = __expf(m2 - mn2);
    m = mn;
    m2 = mn2;

    float rs = 0.f, rs2 = 0.f;
    bf16x8 pa0, pa1, pa2, pa3;
#pragma unroll
    for (int f = 0; f < 4; ++f)
#pragma unroll
      for (int j = 0; j < 4; ++j) {
        const float p = __expf(sv[f][j] - mn);
        const float p2 = __expf(sw[f][j] - mn2);
        rs += p;
        rs2 += p2;
        const bf16 pb = (bf16)p;
        const bf16 pb2 = (bf16)p2;
        if (f == 0) { pa0[j] = pb; pa2[j] = pb2; }
        else if (f == 1) { pa0[4 + j] = pb; pa2[4 + j] = pb2; }
        else if (f == 2) { pa1[j] = pb; pa3[j] = pb2; }
        else { pa1[4 + j] = pb; pa3[4 + j] = pb2; }
      }
    rs += __shfl_xor(rs, 16, 64);
    rs += __shfl_xor(rs, 32, 64);
    rs2 += __shfl_xor(rs2, 16, 64);
    rs2 += __shfl_xor(rs2, 32, 64);
    l = l * resc + rs;
    l2 = l2 * resc2 + rs2;

#pragma unroll
    for (int df = 0; df < 4; ++df) {
      const bf16* vj = LV + (df * 16 + l15) * 64;
      const bf16x8 va0 = *(const bf16x8*)(vj + (lg ^ swz) * 8);
      const bf16x8 va1 = *(const bf16x8*)(vj + ((lg + 4) ^ swz) * 8);
      f32x4 t4 = oacc[df];
      f32x4 u4 = oacc2[df];
#pragma unroll
      for (int j = 0; j < 4; ++j) {
        t4[j] *= resc;
        u4[j] *= resc2;
      }
      t4 = MFMA_16x16x32(va0, pa0, t4);
      u4 = MFMA_16x16x32(va0, pa2, u4);
      t4 = MFMA_16x16x32(va1, pa1, t4);
      u4 = MFMA_16x16x32(va1, pa3, u4);
      oacc[df] = t4;
      oacc2[df] = u4;
    }
    __syncthreads();  // drains vmcnt (stage t+1 done); frees buf[cur]
  }

  const float inv = 1.0f / l;
  const float inv2 = 1.0f / l2;
  const size_t orow = ((size_t)b * 1024 + qbase + l15) * 768 + h * 64;
  const size_t orow2 = orow + (size_t)64 * 768;
#pragma unroll
  for (int df = 0; df < 4; ++df)
#pragma unroll
    for (int r = 0; r < 4; ++r) {
      outws[orow + df * 16 + lg * 4 + r] = (bf16)(oacc[df][r] * inv);
      outws[orow2 + df * 16 + lg * 4 + r] = (bf16)(oacc2[df][r] * inv2);
    }
}

// ---------------------------------------------------------------------------
extern "C" void kernel_launch(void* const* d_in, const int* in_sizes, int n_in,
                              void* d_out, int out_size, void* d_ws, size_t ws_size,
                              hipStream_t stream) {
  const float* x       = (const float*)d_in[0];
  const float* size_in = (const float*)d_in[1];
  const void*  mask    = d_in[2];
  const float* w_qkv   = (const float*)d_in[3];
  const float* w_proj  = (const float*)d_in[4];
  const float* b_proj  = (const float*)d_in[5];
  float* out = (float*)d_out;   // f32 outputs per reference dtype

  if (n_in < 6 ||
      in_sizes[0] != 6291456 || in_sizes[1] != 8192 || in_sizes[2] != 8192 ||
      in_sizes[3] != 1769472 || in_sizes[4] != 589824 || in_sizes[5] != 768)
    return;

  const size_t QS = (size_t)B_ * H_ * N_ * HD_;  // 6291456 elems
  if (ws_size < 55083024) return;

  bf16* xb    = (bf16*)d_ws;       // dead after gemm<0>; reused as attnw
  bf16* qbuf  = xb + QS;
  bf16* kbuf  = qbuf + QS;
  bf16* vtbuf = kbuf + QS;
  bf16* wqb   = vtbuf + QS;        // 1769472 elems
  bf16* wpb   = wqb + 1769472;     // 589824 elems
  float* biasb = (float*)(wpb + 589824);
  int* flags = (int*)(biasb + 8192);
  bf16* attnw = xb;

  hipMemsetAsync(flags, 0, 8, stream);
  detect_mask_kernel<<<8, 256, 0, stream>>>((const unsigned*)mask, flags);
  cvt_kernel<<<6144, 256, 0, stream>>>(x, w_qkv, w_proj, size_in, mask, flags,
                                       xb, wqb, wpb, biasb);
  gemm_bt<0><<<64 * 18, 256, 0, stream>>>(xb, wqb, nullptr, qbuf, kbuf, vtbuf, nullptr);
  kmean_kernel<<<2048, 256, 0, stream>>>(kbuf, out + (size_t)B_ * N_ * C_);
  attn_mfma<<<768, 256, 0, stream>>>(qbuf, kbuf, vtbuf, biasb, attnw);
  gemm_bt<1><<<64 * 6, 256, 0, stream>>>(attnw, wpb, b_proj, nullptr, nullptr, nullptr, out);
}

// Round 12
// 218.257 us; speedup vs baseline: 1.4386x; 1.0026x over previous
//
#include <hip/hip_runtime.h>

typedef __bf16 bf16;
typedef __bf16 bf16x4 __attribute__((ext_vector_type(4)));
typedef __bf16 bf16x8 __attribute__((ext_vector_type(8)));
typedef float f32x4 __attribute__((ext_vector_type(4)));

#define MFMA_16x16x32(a, b, c) __builtin_amdgcn_mfma_f32_16x16x32_bf16((a), (b), (c), 0, 0, 0)

#define B_ 8
#define N_ 1024
#define C_ 768
#define H_ 12
#define HD_ 64
#define KDIM 768

__device__ __forceinline__ void gload_lds16(const void* g, void* l) {
  __builtin_amdgcn_global_load_lds(
      (const __attribute__((address_space(1))) void*)g,
      (__attribute__((address_space(3))) void*)l, 16, 0, 0);
}

// ---------------------------------------------------------------------------
// mask dtype detection (robust to int8/int32/int64 storage)
// ---------------------------------------------------------------------------
__global__ __launch_bounds__(256) void detect_mask_kernel(const unsigned* __restrict__ m32,
                                                          int* __restrict__ flags) {
  const int i = blockIdx.x * 256 + threadIdx.x;
  if (i < 2048) {
    const unsigned v = m32[i];
    if (v > 1u) atomicOr(&flags[0], 1);
    if ((i & 1) && v != 0u) atomicOr(&flags[1], 1);
  }
}

// ---------------------------------------------------------------------------
// cvt: f32 -> bf16 for x, w_qkv, w_proj; bias[b*N+n] = mask ? -1e30 : log(size)
// ---------------------------------------------------------------------------
__global__ __launch_bounds__(256) void cvt_kernel(const float* __restrict__ x,
                                                  const float* __restrict__ wq,
                                                  const float* __restrict__ wp,
                                                  const float* __restrict__ size_in,
                                                  const void* __restrict__ mask_raw,
                                                  const int* __restrict__ flags,
                                                  bf16* __restrict__ xb,
                                                  bf16* __restrict__ wqb,
                                                  bf16* __restrict__ wpb,
                                                  float* __restrict__ biasb) {
  const int i = blockIdx.x * 256 + threadIdx.x;  // grid covers 6291456/4
  {
    const float4 v = ((const float4*)x)[i];
    bf16x4 o = {(bf16)v.x, (bf16)v.y, (bf16)v.z, (bf16)v.w};
    ((bf16x4*)xb)[i] = o;
  }
  if (i < 442368) {  // 2304*768/4
    const float4 v = ((const float4*)wq)[i];
    bf16x4 o = {(bf16)v.x, (bf16)v.y, (bf16)v.z, (bf16)v.w};
    ((bf16x4*)wqb)[i] = o;
  }
  if (i < 147456) {  // 768*768/4
    const float4 v = ((const float4*)wp)[i];
    bf16x4 o = {(bf16)v.x, (bf16)v.y, (bf16)v.z, (bf16)v.w};
    ((bf16x4*)wpb)[i] = o;
  }
  if (i < B_ * N_) {
    int mv;
    if (flags[0]) {
      mv = (int)((const unsigned char*)mask_raw)[i];
    } else if (flags[1]) {
      mv = ((const int*)mask_raw)[i];
    } else {  // int64
      const unsigned* m32 = (const unsigned*)mask_raw;
      mv = (int)(m32[2 * i] | m32[2 * i + 1]);
    }
    biasb[i] = mv ? -1e30f : logf(size_in[i]);
  }
}

// ---------------------------------------------------------------------------
// GEMM (NT): out[m][o] = sum_k A[m][k] * W[o][k].  M=8192, K=768.
// MODE 0: A linear [m][768]; scatter epilogue into q/k/vt
// MODE 1: A in [b][h][n][64] layout (attnw); f32 epilogue outf = acc + bias
//         (k-tile kt lies entirely in head h = kt/64 since BK=64 == HD)
// ---------------------------------------------------------------------------
template <int MODE>
__global__ __launch_bounds__(256) void gemm_bt(const bf16* __restrict__ A,
                                               const bf16* __restrict__ W,
                                               const float* __restrict__ bias,
                                               bf16* __restrict__ out0,
                                               bf16* __restrict__ out1,
                                               bf16* __restrict__ out2,
                                               float* __restrict__ outf) {
  __shared__ bf16 As[128 * 64];
  __shared__ bf16 Bs[128 * 64];
  const int bid = blockIdx.x;
  const int mt = bid % 64;
  const int nt = bid / 64;
  const int t = threadIdx.x;
  const int lane = t & 63, w = t >> 6;
  const int wm = w >> 1, wn = w & 1;
  const int l15 = lane & 15, lg = lane >> 4;

  f32x4 acc[4][4] = {};

  const int srow = t >> 3;
  const int skel = (t & 7) * 8;
  const bf16* Ag = A + (size_t)(mt * 128) * KDIM;
  const bf16* Bg = W + (size_t)(nt * 128) * KDIM;
  const int bA = mt >> 3;              // MODE 1: batch of this M-tile
  const int nbase = (mt & 7) * 128;    // MODE 1: n-base of this M-tile

  for (int kt = 0; kt < KDIM; kt += 64) {
#pragma unroll
    for (int c = 0; c < 4; ++c) {
      const bf16* aSrc;
      if (MODE == 0)
        aSrc = Ag + (size_t)(c * 32 + srow) * KDIM + kt + skel;
      else
        aSrc = A + (((size_t)(bA * 12 + (kt >> 6)) * 1024) + nbase + c * 32 + srow) * 64 + skel;
      gload_lds16(aSrc, (char*)As + c * 4096 + w * 1024);
      gload_lds16(Bg + (size_t)(c * 32 + srow) * KDIM + kt + skel,
                  (char*)Bs + c * 4096 + w * 1024);
    }
    __syncthreads();
#pragma unroll
    for (int ks = 0; ks < 2; ++ks) {
      bf16x8 af[4], bfr[4];
#pragma unroll
      for (int i = 0; i < 4; ++i)
        af[i] = *(const bf16x8*)(As + (wm * 64 + i * 16 + l15) * 64 + ks * 32 + lg * 8);
#pragma unroll
      for (int i = 0; i < 4; ++i)
        bfr[i] = *(const bf16x8*)(Bs + (wn * 64 + i * 16 + l15) * 64 + ks * 32 + lg * 8);
#pragma unroll
      for (int i = 0; i < 4; ++i)
#pragma unroll
        for (int j = 0; j < 4; ++j)
          acc[i][j] = MFMA_16x16x32(af[i], bfr[j], acc[i][j]);
    }
    __syncthreads();
  }

  if (MODE == 0) {
    const int which = (nt * 128) / 768;  // 768 = 6*128, tiles never straddle
#pragma unroll
    for (int i = 0; i < 4; ++i)
#pragma unroll
      for (int j = 0; j < 4; ++j)
#pragma unroll
        for (int r = 0; r < 4; ++r) {
          const int m = mt * 128 + wm * 64 + i * 16 + lg * 4 + r;
          const int o = nt * 128 + wn * 64 + j * 16 + l15;
          const int b = m >> 10, n = m & 1023;
          const int f = o - which * 768;
          const int h = f >> 6, hd = f & 63;
          const bf16 bv = (bf16)acc[i][j][r];
          if (which == 0)
            out0[(((size_t)(b * 12 + h)) * 1024 + n) * 64 + hd] = bv;
          else if (which == 1)
            out1[(((size_t)(b * 12 + h)) * 1024 + n) * 64 + hd] = bv;
          else
            out2[(((size_t)(b * 12 + h)) * 64 + hd) * 1024 + n] = bv;
        }
  } else {
#pragma unroll
    for (int i = 0; i < 4; ++i)
#pragma unroll
      for (int j = 0; j < 4; ++j) {
        const int o = nt * 128 + wn * 64 + j * 16 + l15;
        const float bv = bias[o];
#pragma unroll
        for (int r = 0; r < 4; ++r) {
          const int m = mt * 128 + wm * 64 + i * 16 + lg * 4 + r;
          outf[(size_t)m * 768 + o] = acc[i][j][r] + bv;
        }
      }
  }
}

// ---------------------------------------------------------------------------
// k_mean (f32 out): kmean[b,n,hd] = mean_h k[b,h,n,hd]
// ---------------------------------------------------------------------------
__global__ __launch_bounds__(256) void kmean_kernel(const bf16* __restrict__ kbuf,
                                                    float* __restrict__ kmean) {
  const int i = blockIdx.x * 256 + threadIdx.x;
  if (i >= B_ * N_ * HD_) return;
  const int hd = i & 63;
  const int n = (i >> 6) & 1023;
  const int b = i >> 16;
  float s = 0.f;
#pragma unroll
  for (int h = 0; h < 12; ++h)
    s += (float)kbuf[(((size_t)(b * 12 + h)) * 1024 + n) * 64 + hd];
  kmean[i] = s * (1.0f / 12.0f);
}

// ---------------------------------------------------------------------------
// MFMA flash attention (R11 structure: 2 q-tiles/block, 4 waves, KBLK=64,
// double-buffered LDS K/V, swapped-operand QK^T, lane-local softmax,
// grid = bh*8 + qt). R12 delta: output stored CONTIGUOUSLY to
// attnw[b][h][n][64] -> each block writes two coalesced 4KB runs
// (write-amp ~1x, kills the 10x partial-line writeback seen in R11).
// ---------------------------------------------------------------------------
__global__ __launch_bounds__(256, 5) void attn_mfma(const bf16* __restrict__ qbuf,
                                                    const bf16* __restrict__ kbuf,
                                                    const bf16* __restrict__ vtbuf,
                                                    const float* __restrict__ biasb,
                                                    bf16* __restrict__ outws) {
  __shared__ bf16 Ks[2][4096];  // [64 rows][8 slots of 8 elems], swizzled
  __shared__ bf16 Vs[2][4096];
  const int id = blockIdx.x;
  const int qt = id & 7;
  const int bh = id >> 3;
  const int b = bh / 12;
  const int t = threadIdx.x, lane = t & 63, w = t >> 6;
  const int l15 = lane & 15, lg = lane >> 4;
  const int qbase = qt * 128 + w * 16;   // tile0 rows; tile1 = qbase + 64

  const bf16* Q = qbuf + ((size_t)bh * 1024 + qbase) * 64;
  const bf16* Kp = kbuf + (size_t)bh * 65536;
  const bf16* Vt = vtbuf + (size_t)bh * 65536;
  const float* bias = biasb + b * 1024;

  // Q as B-operand: col=l15 (q-row), k-slots lg*8+e = d
  const bf16x8 qb0 = *(const bf16x8*)(Q + l15 * 64 + lg * 8);
  const bf16x8 qb1 = *(const bf16x8*)(Q + l15 * 64 + 32 + lg * 8);
  const bf16x8 qc0 = *(const bf16x8*)(Q + (64 + l15) * 64 + lg * 8);
  const bf16x8 qc1 = *(const bf16x8*)(Q + (64 + l15) * 64 + 32 + lg * 8);

  // staging geometry: thread covers LDS 16B slot (row=t>>3 [+32], sl=t&7);
  // phys slot sl holds logical slot sl^(row&7); K row j holds key pi(j).
  const int srow = t >> 3;                 // 0..31
  const int dsl = (t & 7) ^ (srow & 7);    // logical slot fetched
  const int pi0 = 4 * ((srow >> 4) & 1) + 8 * ((srow >> 2) & 3) + (srow & 3);
  const bf16* srcK0 = Kp + pi0 * 64 + dsl * 8;          // rows j = srow
  const bf16* srcK1 = Kp + (32 + pi0) * 64 + dsl * 8;   // rows j = 32+srow
  const bf16* srcV0 = Vt + (size_t)srow * 1024 + dsl * 8;
  const bf16* srcV1 = Vt + (size_t)(32 + srow) * 1024 + dsl * 8;
  char* const ldsK0 = (char*)&Ks[0][0] + w * 1024;
  char* const ldsK1 = (char*)&Ks[1][0] + w * 1024;
  char* const ldsV0 = (char*)&Vs[0][0] + w * 1024;
  char* const ldsV1 = (char*)&Vs[1][0] + w * 1024;

  // prologue: stage tile 0 into buf 0
  gload_lds16(srcK0, ldsK0);
  gload_lds16(srcK1, ldsK0 + 4096);  // rows 32..63 at +4KB
  gload_lds16(srcV0, ldsV0);
  gload_lds16(srcV1, ldsV0 + 4096);
  __syncthreads();

  const int bb0 = 8 * lg;        // bias quad base (D-row=lg*4+j)
  const int swz = l15 & 7;

  f32x4 oacc[4] = {}, oacc2[4] = {};
  float m = -1e30f, l = 0.f;
  float m2 = -1e30f, l2 = 0.f;

  for (int kt = 0; kt < 16; ++kt) {
    const int cur = kt & 1;
    const int kb = kt * 64;
    if (kt < 15) {  // stage next tile into the other buffer
      const size_t ko = (size_t)(kb + 64) * 64;
      char* const nK = cur ? ldsK0 : ldsK1;
      char* const nV = cur ? ldsV0 : ldsV1;
      gload_lds16(srcK0 + ko, nK);
      gload_lds16(srcK1 + ko, nK + 4096);
      gload_lds16(srcV0 + (kb + 64), nV);
      gload_lds16(srcV1 + (kb + 64), nV + 4096);
    }

    const bf16* LK = Ks[cur];
    const bf16* LV = Vs[cur];
    float sv[4][4], sw[4][4];
#pragma unroll
    for (int f = 0; f < 4; ++f) {
      const int cf = 32 * (f >> 1) + 4 * (f & 1);
      const bf16* kj = LK + (f * 16 + l15) * 64;
      const bf16x8 ka0 = *(const bf16x8*)(kj + (lg ^ swz) * 8);
      const bf16x8 ka1 = *(const bf16x8*)(kj + ((lg + 4) ^ swz) * 8);
      f32x4 z = {}, y = {};
      z = MFMA_16x16x32(ka0, qb0, z);
      y = MFMA_16x16x32(ka0, qc0, y);
      z = MFMA_16x16x32(ka1, qb1, z);
      y = MFMA_16x16x32(ka1, qc1, y);
      const float4 bi = *(const float4*)(bias + kb + cf + bb0);
      sv[f][0] = z[0] * 0.125f + bi.x;
      sv[f][1] = z[1] * 0.125f + bi.y;
      sv[f][2] = z[2] * 0.125f + bi.z;
      sv[f][3] = z[3] * 0.125f + bi.w;
      sw[f][0] = y[0] * 0.125f + bi.x;
      sw[f][1] = y[1] * 0.125f + bi.y;
      sw[f][2] = y[2] * 0.125f + bi.z;
      sw[f][3] = y[3] * 0.125f + bi.w;
    }
    // per-tile max over 64 keys: 15 local + 2 shuffles each
    float mx = sv[0][0], mx2 = sw[0][0];
#pragma unroll
    for (int f = 0; f < 4; ++f)
#pragma unroll
      for (int j = 0; j < 4; ++j) {
        mx = fmaxf(mx, sv[f][j]);
        mx2 = fmaxf(mx2, sw[f][j]);
      }
    mx = fmaxf(mx, __shfl_xor(mx, 16, 64));
    mx = fmaxf(mx, __shfl_xor(mx, 32, 64));
    mx2 = fmaxf(mx2, __shfl_xor(mx2, 16, 64));
    mx2 = fmaxf(mx2, __shfl_xor(mx2, 32, 64));
    const float mn = fmaxf(m, mx);
    const float mn2 = fmaxf(m2, mx2);
    const float resc = __expf(m - mn);
    const float resc2 = __expf(m2 - mn2);
    m = mn;
    m2 = mn2;

    float rs = 0.f, rs2 = 0.f;
    bf16x8 pa0, pa1, pa2, pa3;
#pragma unroll
    for (int f = 0; f < 4; ++f)
#pragma unroll
      for (int j = 0; j < 4; ++j) {
        const float p = __expf(sv[f][j] - mn);
        const float p2 = __expf(sw[f][j] - mn2);
        rs += p;
        rs2 += p2;
        const bf16 pb = (bf16)p;
        const bf16 pb2 = (bf16)p2;
        if (f == 0) { pa0[j] = pb; pa2[j] = pb2; }
        else if (f == 1) { pa0[4 + j] = pb; pa2[4 + j] = pb2; }
        else if (f == 2) { pa1[j] = pb; pa3[j] = pb2; }
        else { pa1[4 + j] = pb; pa3[4 + j] = pb2; }
      }
    rs += __shfl_xor(rs, 16, 64);
    rs += __shfl_xor(rs, 32, 64);
    rs2 += __shfl_xor(rs2, 16, 64);
    rs2 += __shfl_xor(rs2, 32, 64);
    l = l * resc + rs;
    l2 = l2 * resc2 + rs2;

#pragma unroll
    for (int df = 0; df < 4; ++df) {
      const bf16* vj = LV + (df * 16 + l15) * 64;
      const bf16x8 va0 = *(const bf16x8*)(vj + (lg ^ swz) * 8);
      const bf16x8 va1 = *(const bf16x8*)(vj + ((lg + 4) ^ swz) * 8);
      f32x4 t4 = oacc[df];
      f32x4 u4 = oacc2[df];
#pragma unroll
      for (int j = 0; j < 4; ++j) {
        t4[j] *= resc;
        u4[j] *= resc2;
      }
      t4 = MFMA_16x16x32(va0, pa0, t4);
      u4 = MFMA_16x16x32(va0, pa2, u4);
      t4 = MFMA_16x16x32(va1, pa1, t4);
      u4 = MFMA_16x16x32(va1, pa3, u4);
      oacc[df] = t4;
      oacc2[df] = u4;
    }
    __syncthreads();  // drains vmcnt (stage t+1 done); frees buf[cur]
  }

  // contiguous store: attnw[b][h][n][64]; tile0 rows qbase.., tile1 +64
  const float inv = 1.0f / l;
  const float inv2 = 1.0f / l2;
  bf16* outp = outws + ((size_t)bh * 1024 + qbase + l15) * 64;
#pragma unroll
  for (int df = 0; df < 4; ++df) {
    bf16x4 ov = {(bf16)(oacc[df][0] * inv), (bf16)(oacc[df][1] * inv),
                 (bf16)(oacc[df][2] * inv), (bf16)(oacc[df][3] * inv)};
    *(bf16x4*)(outp + df * 16 + lg * 4) = ov;
    bf16x4 ov2 = {(bf16)(oacc2[df][0] * inv2), (bf16)(oacc2[df][1] * inv2),
                  (bf16)(oacc2[df][2] * inv2), (bf16)(oacc2[df][3] * inv2)};
    *(bf16x4*)(outp + (size_t)64 * 64 + df * 16 + lg * 4) = ov2;
  }
}

// ---------------------------------------------------------------------------
extern "C" void kernel_launch(void* const* d_in, const int* in_sizes, int n_in,
                              void* d_out, int out_size, void* d_ws, size_t ws_size,
                              hipStream_t stream) {
  const float* x       = (const float*)d_in[0];
  const float* size_in = (const float*)d_in[1];
  const void*  mask    = d_in[2];
  const float* w_qkv   = (const float*)d_in[3];
  const float* w_proj  = (const float*)d_in[4];
  const float* b_proj  = (const float*)d_in[5];
  float* out = (float*)d_out;   // f32 outputs per reference dtype

  if (n_in < 6 ||
      in_sizes[0] != 6291456 || in_sizes[1] != 8192 || in_sizes[2] != 8192 ||
      in_sizes[3] != 1769472 || in_sizes[4] != 589824 || in_sizes[5] != 768)
    return;

  const size_t QS = (size_t)B_ * H_ * N_ * HD_;  // 6291456 elems
  if (ws_size < 55083024) return;

  bf16* xb    = (bf16*)d_ws;       // dead after gemm<0>; reused as attnw
  bf16* qbuf  = xb + QS;
  bf16* kbuf  = qbuf + QS;
  bf16* vtbuf = kbuf + QS;
  bf16* wqb   = vtbuf + QS;        // 1769472 elems
  bf16* wpb   = wqb + 1769472;     // 589824 elems
  float* biasb = (float*)(wpb + 589824);
  int* flags = (int*)(biasb + 8192);
  bf16* attnw = xb;                // [b][h][n][64]

  hipMemsetAsync(flags, 0, 8, stream);
  detect_mask_kernel<<<8, 256, 0, stream>>>((const unsigned*)mask, flags);
  cvt_kernel<<<6144, 256, 0, stream>>>(x, w_qkv, w_proj, size_in, mask, flags,
                                       xb, wqb, wpb, biasb);
  gemm_bt<0><<<64 * 18, 256, 0, stream>>>(xb, wqb, nullptr, qbuf, kbuf, vtbuf, nullptr);
  kmean_kernel<<<2048, 256, 0, stream>>>(kbuf, out + (size_t)B_ * N_ * C_);
  attn_mfma<<<768, 256, 0, stream>>>(qbuf, kbuf, vtbuf, biasb, attnw);
  gemm_bt<1><<<64 * 6, 256, 0, stream>>>(attnw, wpb, b_proj, nullptr, nullptr, nullptr, out);
}

// Round 13
// 176.876 us; speedup vs baseline: 1.7752x; 1.2340x over previous
//
#include <hip/hip_runtime.h>

typedef __bf16 bf16;
typedef __bf16 bf16x4 __attribute__((ext_vector_type(4)));
typedef __bf16 bf16x8 __attribute__((ext_vector_type(8)));
typedef float f32x4 __attribute__((ext_vector_type(4)));

#define MFMA_16x16x32(a, b, c) __builtin_amdgcn_mfma_f32_16x16x32_bf16((a), (b), (c), 0, 0, 0)

#define B_ 8
#define N_ 1024
#define C_ 768
#define H_ 12
#define HD_ 64
#define KDIM 768

__device__ __forceinline__ void gload_lds16(const void* g, void* l) {
  __builtin_amdgcn_global_load_lds(
      (const __attribute__((address_space(1))) void*)g,
      (__attribute__((address_space(3))) void*)l, 16, 0, 0);
}

// ---------------------------------------------------------------------------
// mask dtype detection (robust to int8/int32/int64 storage)
// ---------------------------------------------------------------------------
__global__ __launch_bounds__(256) void detect_mask_kernel(const unsigned* __restrict__ m32,
                                                          int* __restrict__ flags) {
  const int i = blockIdx.x * 256 + threadIdx.x;
  if (i < 2048) {
    const unsigned v = m32[i];
    if (v > 1u) atomicOr(&flags[0], 1);
    if ((i & 1) && v != 0u) atomicOr(&flags[1], 1);
  }
}

// ---------------------------------------------------------------------------
// cvt: f32 -> bf16 for x, w_qkv, w_proj; bias[b*N+n] = mask ? -1e30 : log(size)
// ---------------------------------------------------------------------------
__global__ __launch_bounds__(256) void cvt_kernel(const float* __restrict__ x,
                                                  const float* __restrict__ wq,
                                                  const float* __restrict__ wp,
                                                  const float* __restrict__ size_in,
                                                  const void* __restrict__ mask_raw,
                                                  const int* __restrict__ flags,
                                                  bf16* __restrict__ xb,
                                                  bf16* __restrict__ wqb,
                                                  bf16* __restrict__ wpb,
                                                  float* __restrict__ biasb) {
  const int i = blockIdx.x * 256 + threadIdx.x;  // grid covers 6291456/4
  {
    const float4 v = ((const float4*)x)[i];
    bf16x4 o = {(bf16)v.x, (bf16)v.y, (bf16)v.z, (bf16)v.w};
    ((bf16x4*)xb)[i] = o;
  }
  if (i < 442368) {  // 2304*768/4
    const float4 v = ((const float4*)wq)[i];
    bf16x4 o = {(bf16)v.x, (bf16)v.y, (bf16)v.z, (bf16)v.w};
    ((bf16x4*)wqb)[i] = o;
  }
  if (i < 147456) {  // 768*768/4
    const float4 v = ((const float4*)wp)[i];
    bf16x4 o = {(bf16)v.x, (bf16)v.y, (bf16)v.z, (bf16)v.w};
    ((bf16x4*)wpb)[i] = o;
  }
  if (i < B_ * N_) {
    int mv;
    if (flags[0]) {
      mv = (int)((const unsigned char*)mask_raw)[i];
    } else if (flags[1]) {
      mv = ((const int*)mask_raw)[i];
    } else {  // int64
      const unsigned* m32 = (const unsigned*)mask_raw;
      mv = (int)(m32[2 * i] | m32[2 * i + 1]);
    }
    biasb[i] = mv ? -1e30f : logf(size_in[i]);
  }
}

// ---------------------------------------------------------------------------
// GEMM (NT): out[m][o] = sum_k A[m][k] * W[o][k].  M=8192, K=768.
// MODE 0: A linear [m][768]; scatter epilogue into q/k/vt
// MODE 1: A in [b][h][n][64] layout (attnw); f32 epilogue outf = acc + bias
//         (k-tile kt lies entirely in head h = kt/64 since BK=64 == HD)
// ---------------------------------------------------------------------------
template <int MODE>
__global__ __launch_bounds__(256) void gemm_bt(const bf16* __restrict__ A,
                                               const bf16* __restrict__ W,
                                               const float* __restrict__ bias,
                                               bf16* __restrict__ out0,
                                               bf16* __restrict__ out1,
                                               bf16* __restrict__ out2,
                                               float* __restrict__ outf) {
  __shared__ bf16 As[128 * 64];
  __shared__ bf16 Bs[128 * 64];
  const int bid = blockIdx.x;
  const int mt = bid % 64;
  const int nt = bid / 64;
  const int t = threadIdx.x;
  const int lane = t & 63, w = t >> 6;
  const int wm = w >> 1, wn = w & 1;
  const int l15 = lane & 15, lg = lane >> 4;

  f32x4 acc[4][4] = {};

  const int srow = t >> 3;
  const int skel = (t & 7) * 8;
  const bf16* Ag = A + (size_t)(mt * 128) * KDIM;
  const bf16* Bg = W + (size_t)(nt * 128) * KDIM;
  const int bA = mt >> 3;              // MODE 1: batch of this M-tile
  const int nbase = (mt & 7) * 128;    // MODE 1: n-base of this M-tile

  for (int kt = 0; kt < KDIM; kt += 64) {
#pragma unroll
    for (int c = 0; c < 4; ++c) {
      const bf16* aSrc;
      if (MODE == 0)
        aSrc = Ag + (size_t)(c * 32 + srow) * KDIM + kt + skel;
      else
        aSrc = A + (((size_t)(bA * 12 + (kt >> 6)) * 1024) + nbase + c * 32 + srow) * 64 + skel;
      gload_lds16(aSrc, (char*)As + c * 4096 + w * 1024);
      gload_lds16(Bg + (size_t)(c * 32 + srow) * KDIM + kt + skel,
                  (char*)Bs + c * 4096 + w * 1024);
    }
    __syncthreads();
#pragma unroll
    for (int ks = 0; ks < 2; ++ks) {
      bf16x8 af[4], bfr[4];
#pragma unroll
      for (int i = 0; i < 4; ++i)
        af[i] = *(const bf16x8*)(As + (wm * 64 + i * 16 + l15) * 64 + ks * 32 + lg * 8);
#pragma unroll
      for (int i = 0; i < 4; ++i)
        bfr[i] = *(const bf16x8*)(Bs + (wn * 64 + i * 16 + l15) * 64 + ks * 32 + lg * 8);
#pragma unroll
      for (int i = 0; i < 4; ++i)
#pragma unroll
        for (int j = 0; j < 4; ++j)
          acc[i][j] = MFMA_16x16x32(af[i], bfr[j], acc[i][j]);
    }
    __syncthreads();
  }

  if (MODE == 0) {
    const int which = (nt * 128) / 768;  // 768 = 6*128, tiles never straddle
#pragma unroll
    for (int i = 0; i < 4; ++i)
#pragma unroll
      for (int j = 0; j < 4; ++j)
#pragma unroll
        for (int r = 0; r < 4; ++r) {
          const int m = mt * 128 + wm * 64 + i * 16 + lg * 4 + r;
          const int o = nt * 128 + wn * 64 + j * 16 + l15;
          const int b = m >> 10, n = m & 1023;
          const int f = o - which * 768;
          const int h = f >> 6, hd = f & 63;
          const bf16 bv = (bf16)acc[i][j][r];
          if (which == 0)
            out0[(((size_t)(b * 12 + h)) * 1024 + n) * 64 + hd] = bv;
          else if (which == 1)
            out1[(((size_t)(b * 12 + h)) * 1024 + n) * 64 + hd] = bv;
          else
            out2[(((size_t)(b * 12 + h)) * 64 + hd) * 1024 + n] = bv;
        }
  } else {
#pragma unroll
    for (int i = 0; i < 4; ++i)
#pragma unroll
      for (int j = 0; j < 4; ++j) {
        const int o = nt * 128 + wn * 64 + j * 16 + l15;
        const float bv = bias[o];
#pragma unroll
        for (int r = 0; r < 4; ++r) {
          const int m = mt * 128 + wm * 64 + i * 16 + lg * 4 + r;
          outf[(size_t)m * 768 + o] = acc[i][j][r] + bv;
        }
      }
  }
}

// ---------------------------------------------------------------------------
// k_mean (f32 out): kmean[b,n,hd] = mean_h k[b,h,n,hd]
// ---------------------------------------------------------------------------
__global__ __launch_bounds__(256) void kmean_kernel(const bf16* __restrict__ kbuf,
                                                    float* __restrict__ kmean) {
  const int i = blockIdx.x * 256 + threadIdx.x;
  if (i >= B_ * N_ * HD_) return;
  const int hd = i & 63;
  const int n = (i >> 6) & 1023;
  const int b = i >> 16;
  float s = 0.f;
#pragma unroll
  for (int h = 0; h < 12; ++h)
    s += (float)kbuf[(((size_t)(b * 12 + h)) * 1024 + n) * 64 + hd];
  kmean[i] = s * (1.0f / 12.0f);
}

// ---------------------------------------------------------------------------
// MFMA flash attention. Block = 8 waves (512 thr), each wave 2 q-tiles of 16
// rows -> 256 q-rows/block; grid = 96 bh x 4 qt (id = bh*4 + qt). Only FOUR
// blocks stream each bh's K/V -> HBM fetch floor ~111MB INDEPENDENT of the
// (uncontrollable) workgroup->XCD mapping. KBLK=64, double-buffered LDS K/V
// via global_load_lds (512-thr staging validated in R9), swapped-operand
// QK^T, lane-local softmax, contiguous [b][h][n][64] store.
// ---------------------------------------------------------------------------
__global__ __launch_bounds__(512, 4) void attn_mfma(const bf16* __restrict__ qbuf,
                                                    const bf16* __restrict__ kbuf,
                                                    const bf16* __restrict__ vtbuf,
                                                    const float* __restrict__ biasb,
                                                    bf16* __restrict__ outws) {
  __shared__ bf16 Ks[2][4096];  // [64 rows][8 slots of 8 elems], swizzled
  __shared__ bf16 Vs[2][4096];
  const int id = blockIdx.x;
  const int qt = id & 3;
  const int bh = id >> 2;
  const int b = bh / 12;
  const int t = threadIdx.x, lane = t & 63, w = t >> 6;  // w 0..7
  const int l15 = lane & 15, lg = lane >> 4;
  const int qbase = qt * 256 + w * 16;   // tile0 rows; tile1 = qbase + 128

  const bf16* Q = qbuf + ((size_t)bh * 1024 + qbase) * 64;
  const bf16* Kp = kbuf + (size_t)bh * 65536;
  const bf16* Vt = vtbuf + (size_t)bh * 65536;
  const float* bias = biasb + b * 1024;

  // Q as B-operand: col=l15 (q-row), k-slots lg*8+e = d
  const bf16x8 qb0 = *(const bf16x8*)(Q + l15 * 64 + lg * 8);
  const bf16x8 qb1 = *(const bf16x8*)(Q + l15 * 64 + 32 + lg * 8);
  const bf16x8 qc0 = *(const bf16x8*)(Q + (128 + l15) * 64 + lg * 8);
  const bf16x8 qc1 = *(const bf16x8*)(Q + (128 + l15) * 64 + 32 + lg * 8);

  // staging (512-thr, R9-validated): thread t fills LDS bytes [t*16, t*16+16)
  // of each 8KB tile. K row srow holds key pi(srow); phys slot (t&7) holds
  // logical slot (t&7)^(srow&7)  (bank swizzle via pre-swizzled source).
  const int srow = t >> 3;                 // 0..63
  const int dsl = (t & 7) ^ (srow & 7);
  const int kkey = 32 * ((srow >> 5) & 1) + 4 * ((srow >> 4) & 1) +
                   8 * ((srow >> 2) & 3) + (srow & 3);
  const bf16* srcK = Kp + kkey * 64 + dsl * 8;
  const bf16* srcV = Vt + (size_t)srow * 1024 + dsl * 8;

  gload_lds16(srcK, (char*)&Ks[0][0] + w * 1024);
  gload_lds16(srcV, (char*)&Vs[0][0] + w * 1024);
  __syncthreads();

  const int bb0 = 8 * lg;        // bias quad base (D-row=lg*4+j)
  const int swz = l15 & 7;

  f32x4 oacc[4] = {}, oacc2[4] = {};
  float m = -1e30f, l = 0.f;
  float m2 = -1e30f, l2 = 0.f;

  for (int kt = 0; kt < 16; ++kt) {
    const int cur = kt & 1;
    const int kb = kt * 64;
    if (kt < 15) {  // stage next tile into the other buffer
      gload_lds16(srcK + (size_t)(kb + 64) * 64, (char*)&Ks[cur ^ 1][0] + w * 1024);
      gload_lds16(srcV + (kb + 64), (char*)&Vs[cur ^ 1][0] + w * 1024);
    }

    const bf16* LK = Ks[cur];
    const bf16* LV = Vs[cur];
    float sv[4][4], sw[4][4];
#pragma unroll
    for (int f = 0; f < 4; ++f) {
      const int cf = 32 * (f >> 1) + 4 * (f & 1);
      const bf16* kj = LK + (f * 16 + l15) * 64;
      const bf16x8 ka0 = *(const bf16x8*)(kj + (lg ^ swz) * 8);
      const bf16x8 ka1 = *(const bf16x8*)(kj + ((lg + 4) ^ swz) * 8);
      f32x4 z = {}, y = {};
      z = MFMA_16x16x32(ka0, qb0, z);
      y = MFMA_16x16x32(ka0, qc0, y);
      z = MFMA_16x16x32(ka1, qb1, z);
      y = MFMA_16x16x32(ka1, qc1, y);
      const float4 bi = *(const float4*)(bias + kb + cf + bb0);
      sv[f][0] = z[0] * 0.125f + bi.x;
      sv[f][1] = z[1] * 0.125f + bi.y;
      sv[f][2] = z[2] * 0.125f + bi.z;
      sv[f][3] = z[3] * 0.125f + bi.w;
      sw[f][0] = y[0] * 0.125f + bi.x;
      sw[f][1] = y[1] * 0.125f + bi.y;
      sw[f][2] = y[2] * 0.125f + bi.z;
      sw[f][3] = y[3] * 0.125f + bi.w;
    }
    // per-tile max over 64 keys: 15 local + 2 shuffles each
    float mx = sv[0][0], mx2 = sw[0][0];
#pragma unroll
    for (int f = 0; f < 4; ++f)
#pragma unroll
      for (int j = 0; j < 4; ++j) {
        mx = fmaxf(mx, sv[f][j]);
        mx2 = fmaxf(mx2, sw[f][j]);
      }
    mx = fmaxf(mx, __shfl_xor(mx, 16, 64));
    mx = fmaxf(mx, __shfl_xor(mx, 32, 64));
    mx2 = fmaxf(mx2, __shfl_xor(mx2, 16, 64));
    mx2 = fmaxf(mx2, __shfl_xor(mx2, 32, 64));
    const float mn = fmaxf(m, mx);
    const float mn2 = fmaxf(m2, mx2);
    const float resc = __expf(m - mn);
    const float resc2 = __expf(m2 - mn2);
    m = mn;
    m2 = mn2;

    float rs = 0.f, rs2 = 0.f;
    bf16x8 pa0, pa1, pa2, pa3;
#pragma unroll
    for (int f = 0; f < 4; ++f)
#pragma unroll
      for (int j = 0; j < 4; ++j) {
        const float p = __expf(sv[f][j] - mn);
        const float p2 = __expf(sw[f][j] - mn2);
        rs += p;
        rs2 += p2;
        const bf16 pb = (bf16)p;
        const bf16 pb2 = (bf16)p2;
        if (f == 0) { pa0[j] = pb; pa2[j] = pb2; }
        else if (f == 1) { pa0[4 + j] = pb; pa2[4 + j] = pb2; }
        else if (f == 2) { pa1[j] = pb; pa3[j] = pb2; }
        else { pa1[4 + j] = pb; pa3[4 + j] = pb2; }
      }
    rs += __shfl_xor(rs, 16, 64);
    rs += __shfl_xor(rs, 32, 64);
    rs2 += __shfl_xor(rs2, 16, 64);
    rs2 += __shfl_xor(rs2, 32, 64);
    l = l * resc + rs;
    l2 = l2 * resc2 + rs2;

#pragma unroll
    for (int df = 0; df < 4; ++df) {
      const bf16* vj = LV + (df * 16 + l15) * 64;
      const bf16x8 va0 = *(const bf16x8*)(vj + (lg ^ swz) * 8);
      const bf16x8 va1 = *(const bf16x8*)(vj + ((lg + 4) ^ swz) * 8);
      f32x4 t4 = oacc[df];
      f32x4 u4 = oacc2[df];
#pragma unroll
      for (int j = 0; j < 4; ++j) {
        t4[j] *= resc;
        u4[j] *= resc2;
      }
      t4 = MFMA_16x16x32(va0, pa0, t4);
      u4 = MFMA_16x16x32(va0, pa2, u4);
      t4 = MFMA_16x16x32(va1, pa1, t4);
      u4 = MFMA_16x16x32(va1, pa3, u4);
      oacc[df] = t4;
      oacc2[df] = u4;
    }
    __syncthreads();  // drains vmcnt (stage t+1 done); frees buf[cur]
  }

  // contiguous store: attnw[b][h][n][64]; tile0 rows qbase.., tile1 +128
  const float inv = 1.0f / l;
  const float inv2 = 1.0f / l2;
  bf16* outp = outws + ((size_t)bh * 1024 + qbase + l15) * 64;
#pragma unroll
  for (int df = 0; df < 4; ++df) {
    bf16x4 ov = {(bf16)(oacc[df][0] * inv), (bf16)(oacc[df][1] * inv),
                 (bf16)(oacc[df][2] * inv), (bf16)(oacc[df][3] * inv)};
    *(bf16x4*)(outp + df * 16 + lg * 4) = ov;
    bf16x4 ov2 = {(bf16)(oacc2[df][0] * inv2), (bf16)(oacc2[df][1] * inv2),
                  (bf16)(oacc2[df][2] * inv2), (bf16)(oacc2[df][3] * inv2)};
    *(bf16x4*)(outp + (size_t)128 * 64 + df * 16 + lg * 4) = ov2;
  }
}

// ---------------------------------------------------------------------------
extern "C" void kernel_launch(void* const* d_in, const int* in_sizes, int n_in,
                              void* d_out, int out_size, void* d_ws, size_t ws_size,
                              hipStream_t stream) {
  const float* x       = (const float*)d_in[0];
  const float* size_in = (const float*)d_in[1];
  const void*  mask    = d_in[2];
  const float* w_qkv   = (const float*)d_in[3];
  const float* w_proj  = (const float*)d_in[4];
  const float* b_proj  = (const float*)d_in[5];
  float* out = (float*)d_out;   // f32 outputs per reference dtype

  if (n_in < 6 ||
      in_sizes[0] != 6291456 || in_sizes[1] != 8192 || in_sizes[2] != 8192 ||
      in_sizes[3] != 1769472 || in_sizes[4] != 589824 || in_sizes[5] != 768)
    return;

  const size_t QS = (size_t)B_ * H_ * N_ * HD_;  // 6291456 elems
  if (ws_size < 55083024) return;

  bf16* xb    = (bf16*)d_ws;       // dead after gemm<0>; reused as attnw
  bf16* qbuf  = xb + QS;
  bf16* kbuf  = qbuf + QS;
  bf16* vtbuf = kbuf + QS;
  bf16* wqb   = vtbuf + QS;        // 1769472 elems
  bf16* wpb   = wqb + 1769472;     // 589824 elems
  float* biasb = (float*)(wpb + 589824);
  int* flags = (int*)(biasb + 8192);
  bf16* attnw = xb;                // [b][h][n][64]

  hipMemsetAsync(flags, 0, 8, stream);
  detect_mask_kernel<<<8, 256, 0, stream>>>((const unsigned*)mask, flags);
  cvt_kernel<<<6144, 256, 0, stream>>>(x, w_qkv, w_proj, size_in, mask, flags,
                                       xb, wqb, wpb, biasb);
  gemm_bt<0><<<64 * 18, 256, 0, stream>>>(xb, wqb, nullptr, qbuf, kbuf, vtbuf, nullptr);
  kmean_kernel<<<2048, 256, 0, stream>>>(kbuf, out + (size_t)B_ * N_ * C_);
  attn_mfma<<<384, 512, 0, stream>>>(qbuf, kbuf, vtbuf, biasb, attnw);
  gemm_bt<1><<<64 * 6, 256, 0, stream>>>(attnw, wpb, b_proj, nullptr, nullptr, nullptr, out);
}

// Round 14
// 170.740 us; speedup vs baseline: 1.8390x; 1.0359x over previous
//
#include <hip/hip_runtime.h>

typedef __bf16 bf16;
typedef __bf16 bf16x4 __attribute__((ext_vector_type(4)));
typedef __bf16 bf16x8 __attribute__((ext_vector_type(8)));
typedef float f32x4 __attribute__((ext_vector_type(4)));

#define MFMA_16x16x32(a, b, c) __builtin_amdgcn_mfma_f32_16x16x32_bf16((a), (b), (c), 0, 0, 0)

#define B_ 8
#define N_ 1024
#define C_ 768
#define H_ 12
#define HD_ 64
#define KDIM 768

__device__ __forceinline__ void gload_lds16(const void* g, void* l) {
  __builtin_amdgcn_global_load_lds(
      (const __attribute__((address_space(1))) void*)g,
      (__attribute__((address_space(3))) void*)l, 16, 0, 0);
}

// ---------------------------------------------------------------------------
// mask dtype detection (robust to int8/int32/int64 storage)
// ---------------------------------------------------------------------------
__global__ __launch_bounds__(256) void detect_mask_kernel(const unsigned* __restrict__ m32,
                                                          int* __restrict__ flags) {
  const int i = blockIdx.x * 256 + threadIdx.x;
  if (i < 2048) {
    const unsigned v = m32[i];
    if (v > 1u) atomicOr(&flags[0], 1);
    if ((i & 1) && v != 0u) atomicOr(&flags[1], 1);
  }
}

// ---------------------------------------------------------------------------
// cvt: f32 -> bf16 for x, w_qkv, w_proj; bias[b*N+n] = mask ? -1e30 : log(size)
// ---------------------------------------------------------------------------
__global__ __launch_bounds__(256) void cvt_kernel(const float* __restrict__ x,
                                                  const float* __restrict__ wq,
                                                  const float* __restrict__ wp,
                                                  const float* __restrict__ size_in,
                                                  const void* __restrict__ mask_raw,
                                                  const int* __restrict__ flags,
                                                  bf16* __restrict__ xb,
                                                  bf16* __restrict__ wqb,
                                                  bf16* __restrict__ wpb,
                                                  float* __restrict__ biasb) {
  const int i = blockIdx.x * 256 + threadIdx.x;  // grid covers 6291456/4
  {
    const float4 v = ((const float4*)x)[i];
    bf16x4 o = {(bf16)v.x, (bf16)v.y, (bf16)v.z, (bf16)v.w};
    ((bf16x4*)xb)[i] = o;
  }
  if (i < 442368) {  // 2304*768/4
    const float4 v = ((const float4*)wq)[i];
    bf16x4 o = {(bf16)v.x, (bf16)v.y, (bf16)v.z, (bf16)v.w};
    ((bf16x4*)wqb)[i] = o;
  }
  if (i < 147456) {  // 768*768/4
    const float4 v = ((const float4*)wp)[i];
    bf16x4 o = {(bf16)v.x, (bf16)v.y, (bf16)v.z, (bf16)v.w};
    ((bf16x4*)wpb)[i] = o;
  }
  if (i < B_ * N_) {
    int mv;
    if (flags[0]) {
      mv = (int)((const unsigned char*)mask_raw)[i];
    } else if (flags[1]) {
      mv = ((const int*)mask_raw)[i];
    } else {  // int64
      const unsigned* m32 = (const unsigned*)mask_raw;
      mv = (int)(m32[2 * i] | m32[2 * i + 1]);
    }
    biasb[i] = mv ? -1e30f : logf(size_in[i]);
  }
}

// ---------------------------------------------------------------------------
// GEMM (NT): out[m][o] = sum_k A[m][k] * W[o][k].  M=8192, K=768.
// R14: double-buffered LDS + ONE barrier per K-step (attn-proven structure):
// stage tile kt+1 while computing tile kt; the end-of-step __syncthreads
// drains the in-flight global_load_lds after a full compute phase.
// MODE 0: A linear [m][768]; scatter epilogue into q/k/vt
// MODE 1: A in [b][h][n][64] layout (attnw); f32 epilogue outf = acc + bias
// ---------------------------------------------------------------------------
template <int MODE>
__global__ __launch_bounds__(256) void gemm_bt(const bf16* __restrict__ A,
                                               const bf16* __restrict__ W,
                                               const float* __restrict__ bias,
                                               bf16* __restrict__ out0,
                                               bf16* __restrict__ out1,
                                               bf16* __restrict__ out2,
                                               float* __restrict__ outf) {
  __shared__ bf16 As[2][128 * 64];
  __shared__ bf16 Bs[2][128 * 64];
  const int bid = blockIdx.x;
  const int mt = bid % 64;
  const int nt = bid / 64;
  const int t = threadIdx.x;
  const int lane = t & 63, w = t >> 6;
  const int wm = w >> 1, wn = w & 1;
  const int l15 = lane & 15, lg = lane >> 4;

  f32x4 acc[4][4] = {};

  const int srow = t >> 3;
  const int skel = (t & 7) * 8;
  const bf16* Ag = A + (size_t)(mt * 128) * KDIM;
  const bf16* Bg = W + (size_t)(nt * 128) * KDIM;
  const int bA = mt >> 3;              // MODE 1: batch of this M-tile
  const int nbase = (mt & 7) * 128;    // MODE 1: n-base of this M-tile

  // A/B global source for K-step st (element offset st*64), chunk c
#define ASRC(st, c)                                                          \
  ((MODE == 0)                                                               \
       ? (Ag + (size_t)((c) * 32 + srow) * KDIM + (st) * 64 + skel)          \
       : (A + (((size_t)(bA * 12 + (st)) * 1024) + nbase + (c) * 32 + srow)  \
              * 64 + skel))
#define BSRC(st, c) (Bg + (size_t)((c) * 32 + srow) * KDIM + (st) * 64 + skel)

  // prologue: stage K-step 0 into buffer 0
#pragma unroll
  for (int c = 0; c < 4; ++c) {
    gload_lds16(ASRC(0, c), (char*)As[0] + c * 4096 + w * 1024);
    gload_lds16(BSRC(0, c), (char*)Bs[0] + c * 4096 + w * 1024);
  }
  __syncthreads();

  for (int st = 0; st < KDIM / 64; ++st) {
    const int cur = st & 1;
    if (st < KDIM / 64 - 1) {  // stage next K-step into the other buffer
#pragma unroll
      for (int c = 0; c < 4; ++c) {
        gload_lds16(ASRC(st + 1, c), (char*)As[cur ^ 1] + c * 4096 + w * 1024);
        gload_lds16(BSRC(st + 1, c), (char*)Bs[cur ^ 1] + c * 4096 + w * 1024);
      }
    }
#pragma unroll
    for (int ks = 0; ks < 2; ++ks) {
      bf16x8 af[4], bfr[4];
#pragma unroll
      for (int i = 0; i < 4; ++i)
        af[i] = *(const bf16x8*)(As[cur] + (wm * 64 + i * 16 + l15) * 64 + ks * 32 + lg * 8);
#pragma unroll
      for (int i = 0; i < 4; ++i)
        bfr[i] = *(const bf16x8*)(Bs[cur] + (wn * 64 + i * 16 + l15) * 64 + ks * 32 + lg * 8);
#pragma unroll
      for (int i = 0; i < 4; ++i)
#pragma unroll
        for (int j = 0; j < 4; ++j)
          acc[i][j] = MFMA_16x16x32(af[i], bfr[j], acc[i][j]);
    }
    __syncthreads();  // drains vmcnt (next-tile loads done); frees buf[cur]
  }
#undef ASRC
#undef BSRC

  if (MODE == 0) {
    const int which = (nt * 128) / 768;  // 768 = 6*128, tiles never straddle
#pragma unroll
    for (int i = 0; i < 4; ++i)
#pragma unroll
      for (int j = 0; j < 4; ++j)
#pragma unroll
        for (int r = 0; r < 4; ++r) {
          const int m = mt * 128 + wm * 64 + i * 16 + lg * 4 + r;
          const int o = nt * 128 + wn * 64 + j * 16 + l15;
          const int b = m >> 10, n = m & 1023;
          const int f = o - which * 768;
          const int h = f >> 6, hd = f & 63;
          const bf16 bv = (bf16)acc[i][j][r];
          if (which == 0)
            out0[(((size_t)(b * 12 + h)) * 1024 + n) * 64 + hd] = bv;
          else if (which == 1)
            out1[(((size_t)(b * 12 + h)) * 1024 + n) * 64 + hd] = bv;
          else
            out2[(((size_t)(b * 12 + h)) * 64 + hd) * 1024 + n] = bv;
        }
  } else {
#pragma unroll
    for (int i = 0; i < 4; ++i)
#pragma unroll
      for (int j = 0; j < 4; ++j) {
        const int o = nt * 128 + wn * 64 + j * 16 + l15;
        const float bv = bias[o];
#pragma unroll
        for (int r = 0; r < 4; ++r) {
          const int m = mt * 128 + wm * 64 + i * 16 + lg * 4 + r;
          outf[(size_t)m * 768 + o] = acc[i][j][r] + bv;
        }
      }
  }
}

// ---------------------------------------------------------------------------
// k_mean (f32 out): kmean[b,n,hd] = mean_h k[b,h,n,hd]
// ---------------------------------------------------------------------------
__global__ __launch_bounds__(256) void kmean_kernel(const bf16* __restrict__ kbuf,
                                                    float* __restrict__ kmean) {
  const int i = blockIdx.x * 256 + threadIdx.x;
  if (i >= B_ * N_ * HD_) return;
  const int hd = i & 63;
  const int n = (i >> 6) & 1023;
  const int b = i >> 16;
  float s = 0.f;
#pragma unroll
  for (int h = 0; h < 12; ++h)
    s += (float)kbuf[(((size_t)(b * 12 + h)) * 1024 + n) * 64 + hd];
  kmean[i] = s * (1.0f / 12.0f);
}

// ---------------------------------------------------------------------------
// MFMA flash attention (R13-validated). Block = 8 waves (512 thr), each wave
// 2 q-tiles of 16 rows -> 256 q-rows/block; grid = 96 bh x 4 qt. Only FOUR
// blocks stream each bh's K/V -> HBM fetch floor ~111MB independent of the
// workgroup->XCD mapping. KBLK=64, double-buffered LDS K/V, swapped-operand
// QK^T, lane-local softmax, contiguous [b][h][n][64] store.
// ---------------------------------------------------------------------------
__global__ __launch_bounds__(512, 4) void attn_mfma(const bf16* __restrict__ qbuf,
                                                    const bf16* __restrict__ kbuf,
                                                    const bf16* __restrict__ vtbuf,
                                                    const float* __restrict__ biasb,
                                                    bf16* __restrict__ outws) {
  __shared__ bf16 Ks[2][4096];  // [64 rows][8 slots of 8 elems], swizzled
  __shared__ bf16 Vs[2][4096];
  const int id = blockIdx.x;
  const int qt = id & 3;
  const int bh = id >> 2;
  const int b = bh / 12;
  const int t = threadIdx.x, lane = t & 63, w = t >> 6;  // w 0..7
  const int l15 = lane & 15, lg = lane >> 4;
  const int qbase = qt * 256 + w * 16;   // tile0 rows; tile1 = qbase + 128

  const bf16* Q = qbuf + ((size_t)bh * 1024 + qbase) * 64;
  const bf16* Kp = kbuf + (size_t)bh * 65536;
  const bf16* Vt = vtbuf + (size_t)bh * 65536;
  const float* bias = biasb + b * 1024;

  // Q as B-operand: col=l15 (q-row), k-slots lg*8+e = d
  const bf16x8 qb0 = *(const bf16x8*)(Q + l15 * 64 + lg * 8);
  const bf16x8 qb1 = *(const bf16x8*)(Q + l15 * 64 + 32 + lg * 8);
  const bf16x8 qc0 = *(const bf16x8*)(Q + (128 + l15) * 64 + lg * 8);
  const bf16x8 qc1 = *(const bf16x8*)(Q + (128 + l15) * 64 + 32 + lg * 8);

  // staging: thread t fills LDS bytes [t*16, t*16+16) of each 8KB tile.
  // K row srow holds key pi(srow); phys slot (t&7) holds logical slot
  // (t&7)^(srow&7)  (bank swizzle via pre-swizzled source).
  const int srow = t >> 3;                 // 0..63
  const int dsl = (t & 7) ^ (srow & 7);
  const int kkey = 32 * ((srow >> 5) & 1) + 4 * ((srow >> 4) & 1) +
                   8 * ((srow >> 2) & 3) + (srow & 3);
  const bf16* srcK = Kp + kkey * 64 + dsl * 8;
  const bf16* srcV = Vt + (size_t)srow * 1024 + dsl * 8;

  gload_lds16(srcK, (char*)&Ks[0][0] + w * 1024);
  gload_lds16(srcV, (char*)&Vs[0][0] + w * 1024);
  __syncthreads();

  const int bb0 = 8 * lg;        // bias quad base (D-row=lg*4+j)
  const int swz = l15 & 7;

  f32x4 oacc[4] = {}, oacc2[4] = {};
  float m = -1e30f, l = 0.f;
  float m2 = -1e30f, l2 = 0.f;

  for (int kt = 0; kt < 16; ++kt) {
    const int cur = kt & 1;
    const int kb = kt * 64;
    if (kt < 15) {  // stage next tile into the other buffer
      gload_lds16(srcK + (size_t)(kb + 64) * 64, (char*)&Ks[cur ^ 1][0] + w * 1024);
      gload_lds16(srcV + (kb + 64), (char*)&Vs[cur ^ 1][0] + w * 1024);
    }

    const bf16* LK = Ks[cur];
    const bf16* LV = Vs[cur];
    float sv[4][4], sw[4][4];
#pragma unroll
    for (int f = 0; f < 4; ++f) {
      const int cf = 32 * (f >> 1) + 4 * (f & 1);
      const bf16* kj = LK + (f * 16 + l15) * 64;
      const bf16x8 ka0 = *(const bf16x8*)(kj + (lg ^ swz) * 8);
      const bf16x8 ka1 = *(const bf16x8*)(kj + ((lg + 4) ^ swz) * 8);
      f32x4 z = {}, y = {};
      z = MFMA_16x16x32(ka0, qb0, z);
      y = MFMA_16x16x32(ka0, qc0, y);
      z = MFMA_16x16x32(ka1, qb1, z);
      y = MFMA_16x16x32(ka1, qc1, y);
      const float4 bi = *(const float4*)(bias + kb + cf + bb0);
      sv[f][0] = z[0] * 0.125f + bi.x;
      sv[f][1] = z[1] * 0.125f + bi.y;
      sv[f][2] = z[2] * 0.125f + bi.z;
      sv[f][3] = z[3] * 0.125f + bi.w;
      sw[f][0] = y[0] * 0.125f + bi.x;
      sw[f][1] = y[1] * 0.125f + bi.y;
      sw[f][2] = y[2] * 0.125f + bi.z;
      sw[f][3] = y[3] * 0.125f + bi.w;
    }
    // per-tile max over 64 keys: 15 local + 2 shuffles each
    float mx = sv[0][0], mx2 = sw[0][0];
#pragma unroll
    for (int f = 0; f < 4; ++f)
#pragma unroll
      for (int j = 0; j < 4; ++j) {
        mx = fmaxf(mx, sv[f][j]);
        mx2 = fmaxf(mx2, sw[f][j]);
      }
    mx = fmaxf(mx, __shfl_xor(mx, 16, 64));
    mx = fmaxf(mx, __shfl_xor(mx, 32, 64));
    mx2 = fmaxf(mx2, __shfl_xor(mx2, 16, 64));
    mx2 = fmaxf(mx2, __shfl_xor(mx2, 32, 64));
    const float mn = fmaxf(m, mx);
    const float mn2 = fmaxf(m2, mx2);
    const float resc = __expf(m - mn);
    const float resc2 = __expf(m2 - mn2);
    m = mn;
    m2 = mn2;

    float rs = 0.f, rs2 = 0.f;
    bf16x8 pa0, pa1, pa2, pa3;
#pragma unroll
    for (int f = 0; f < 4; ++f)
#pragma unroll
      for (int j = 0; j < 4; ++j) {
        const float p = __expf(sv[f][j] - mn);
        const float p2 = __expf(sw[f][j] - mn2);
        rs += p;
        rs2 += p2;
        const bf16 pb = (bf16)p;
        const bf16 pb2 = (bf16)p2;
        if (f == 0) { pa0[j] = pb; pa2[j] = pb2; }
        else if (f == 1) { pa0[4 + j] = pb; pa2[4 + j] = pb2; }
        else if (f == 2) { pa1[j] = pb; pa3[j] = pb2; }
        else { pa1[4 + j] = pb; pa3[4 + j] = pb2; }
      }
    rs += __shfl_xor(rs, 16, 64);
    rs += __shfl_xor(rs, 32, 64);
    rs2 += __shfl_xor(rs2, 16, 64);
    rs2 += __shfl_xor(rs2, 32, 64);
    l = l * resc + rs;
    l2 = l2 * resc2 + rs2;

#pragma unroll
    for (int df = 0; df < 4; ++df) {
      const bf16* vj = LV + (df * 16 + l15) * 64;
      const bf16x8 va0 = *(const bf16x8*)(vj + (lg ^ swz) * 8);
      const bf16x8 va1 = *(const bf16x8*)(vj + ((lg + 4) ^ swz) * 8);
      f32x4 t4 = oacc[df];
      f32x4 u4 = oacc2[df];
#pragma unroll
      for (int j = 0; j < 4; ++j) {
        t4[j] *= resc;
        u4[j] *= resc2;
      }
      t4 = MFMA_16x16x32(va0, pa0, t4);
      u4 = MFMA_16x16x32(va0, pa2, u4);
      t4 = MFMA_16x16x32(va1, pa1, t4);
      u4 = MFMA_16x16x32(va1, pa3, u4);
      oacc[df] = t4;
      oacc2[df] = u4;
    }
    __syncthreads();  // drains vmcnt (stage t+1 done); frees buf[cur]
  }

  // contiguous store: attnw[b][h][n][64]; tile0 rows qbase.., tile1 +128
  const float inv = 1.0f / l;
  const float inv2 = 1.0f / l2;
  bf16* outp = outws + ((size_t)bh * 1024 + qbase + l15) * 64;
#pragma unroll
  for (int df = 0; df < 4; ++df) {
    bf16x4 ov = {(bf16)(oacc[df][0] * inv), (bf16)(oacc[df][1] * inv),
                 (bf16)(oacc[df][2] * inv), (bf16)(oacc[df][3] * inv)};
    *(bf16x4*)(outp + df * 16 + lg * 4) = ov;
    bf16x4 ov2 = {(bf16)(oacc2[df][0] * inv2), (bf16)(oacc2[df][1] * inv2),
                  (bf16)(oacc2[df][2] * inv2), (bf16)(oacc2[df][3] * inv2)};
    *(bf16x4*)(outp + (size_t)128 * 64 + df * 16 + lg * 4) = ov2;
  }
}

// ---------------------------------------------------------------------------
extern "C" void kernel_launch(void* const* d_in, const int* in_sizes, int n_in,
                              void* d_out, int out_size, void* d_ws, size_t ws_size,
                              hipStream_t stream) {
  const float* x       = (const float*)d_in[0];
  const float* size_in = (const float*)d_in[1];
  const void*  mask    = d_in[2];
  const float* w_qkv   = (const float*)d_in[3];
  const float* w_proj  = (const float*)d_in[4];
  const float* b_proj  = (const float*)d_in[5];
  float* out = (float*)d_out;   // f32 outputs per reference dtype

  if (n_in < 6 ||
      in_sizes[0] != 6291456 || in_sizes[1] != 8192 || in_sizes[2] != 8192 ||
      in_sizes[3] != 1769472 || in_sizes[4] != 589824 || in_sizes[5] != 768)
    return;

  const size_t QS = (size_t)B_ * H_ * N_ * HD_;  // 6291456 elems
  if (ws_size < 55083024) return;

  bf16* xb    = (bf16*)d_ws;       // dead after gemm<0>; reused as attnw
  bf16* qbuf  = xb + QS;
  bf16* kbuf  = qbuf + QS;
  bf16* vtbuf = kbuf + QS;
  bf16* wqb   = vtbuf + QS;        // 1769472 elems
  bf16* wpb   = wqb + 1769472;     // 589824 elems
  float* biasb = (float*)(wpb + 589824);
  int* flags = (int*)(biasb + 8192);
  bf16* attnw = xb;                // [b][h][n][64]

  hipMemsetAsync(flags, 0, 8, stream);
  detect_mask_kernel<<<8, 256, 0, stream>>>((const unsigned*)mask, flags);
  cvt_kernel<<<6144, 256, 0, stream>>>(x, w_qkv, w_proj, size_in, mask, flags,
                                       xb, wqb, wpb, biasb);
  gemm_bt<0><<<64 * 18, 256, 0, stream>>>(xb, wqb, nullptr, qbuf, kbuf, vtbuf, nullptr);
  kmean_kernel<<<2048, 256, 0, stream>>>(kbuf, out + (size_t)B_ * N_ * C_);
  attn_mfma<<<384, 512, 0, stream>>>(qbuf, kbuf, vtbuf, biasb, attnw);
  gemm_bt<1><<<64 * 6, 256, 0, stream>>>(attnw, wpb, b_proj, nullptr, nullptr, nullptr, out);
}

// Round 15
// 165.524 us; speedup vs baseline: 1.8969x; 1.0315x over previous
//
#include <hip/hip_runtime.h>

typedef __bf16 bf16;
typedef __bf16 bf16x4 __attribute__((ext_vector_type(4)));
typedef __bf16 bf16x8 __attribute__((ext_vector_type(8)));
typedef float f32x4 __attribute__((ext_vector_type(4)));

#define MFMA_16x16x32(a, b, c) __builtin_amdgcn_mfma_f32_16x16x32_bf16((a), (b), (c), 0, 0, 0)

#define B_ 8
#define N_ 1024
#define C_ 768
#define H_ 12
#define HD_ 64
#define KDIM 768

__device__ __forceinline__ void gload_lds16(const void* g, void* l) {
  __builtin_amdgcn_global_load_lds(
      (const __attribute__((address_space(1))) void*)g,
      (__attribute__((address_space(3))) void*)l, 16, 0, 0);
}

// ---------------------------------------------------------------------------
// mask dtype detection (robust to int8/int32/int64 storage)
// ---------------------------------------------------------------------------
__global__ __launch_bounds__(256) void detect_mask_kernel(const unsigned* __restrict__ m32,
                                                          int* __restrict__ flags) {
  const int i = blockIdx.x * 256 + threadIdx.x;
  if (i < 2048) {
    const unsigned v = m32[i];
    if (v > 1u) atomicOr(&flags[0], 1);
    if ((i & 1) && v != 0u) atomicOr(&flags[1], 1);
  }
}

// ---------------------------------------------------------------------------
// cvt: f32 -> bf16 for x, w_qkv, w_proj; bias[b*N+n] = mask ? -1e30 : log(size)
// ---------------------------------------------------------------------------
__global__ __launch_bounds__(256) void cvt_kernel(const float* __restrict__ x,
                                                  const float* __restrict__ wq,
                                                  const float* __restrict__ wp,
                                                  const float* __restrict__ size_in,
                                                  const void* __restrict__ mask_raw,
                                                  const int* __restrict__ flags,
                                                  bf16* __restrict__ xb,
                                                  bf16* __restrict__ wqb,
                                                  bf16* __restrict__ wpb,
                                                  float* __restrict__ biasb) {
  const int i = blockIdx.x * 256 + threadIdx.x;  // grid covers 6291456/4
  {
    const float4 v = ((const float4*)x)[i];
    bf16x4 o = {(bf16)v.x, (bf16)v.y, (bf16)v.z, (bf16)v.w};
    ((bf16x4*)xb)[i] = o;
  }
  if (i < 442368) {  // 2304*768/4
    const float4 v = ((const float4*)wq)[i];
    bf16x4 o = {(bf16)v.x, (bf16)v.y, (bf16)v.z, (bf16)v.w};
    ((bf16x4*)wqb)[i] = o;
  }
  if (i < 147456) {  // 768*768/4
    const float4 v = ((const float4*)wp)[i];
    bf16x4 o = {(bf16)v.x, (bf16)v.y, (bf16)v.z, (bf16)v.w};
    ((bf16x4*)wpb)[i] = o;
  }
  if (i < B_ * N_) {
    int mv;
    if (flags[0]) {
      mv = (int)((const unsigned char*)mask_raw)[i];
    } else if (flags[1]) {
      mv = ((const int*)mask_raw)[i];
    } else {  // int64
      const unsigned* m32 = (const unsigned*)mask_raw;
      mv = (int)(m32[2 * i] | m32[2 * i + 1]);
    }
    biasb[i] = mv ? -1e30f : logf(size_in[i]);
  }
}

// ---------------------------------------------------------------------------
// GEMM (NT): out[m][o] = sum_k A[m][k] * W[o][k].  M=8192, K=768.
// Double-buffered LDS + ONE barrier per K-step (R14) + R15: XOR bank swizzle
// on both LDS tiles. [128][64]-bf16 rows are 128B -> naive frag reads were a
// 16-way bank conflict (SQ_LDS_BANK_CONFLICT 1.06e7). Fix (attn-proven, G21):
// phys 16B slot s of row r holds logical slot s^(r&7); staging pre-swizzles
// the GLOBAL source (LDS dest stays linear for global_load_lds); fragment
// reads use slot (ks*4+lg)^(l15&7). Conflict-free: 2 lanes/bank.
// MODE 0: A linear [m][768]; scatter epilogue into q/k/vt
// MODE 1: A in [b][h][n][64] layout (attnw); f32 epilogue outf = acc + bias
// ---------------------------------------------------------------------------
template <int MODE>
__global__ __launch_bounds__(256) void gemm_bt(const bf16* __restrict__ A,
                                               const bf16* __restrict__ W,
                                               const float* __restrict__ bias,
                                               bf16* __restrict__ out0,
                                               bf16* __restrict__ out1,
                                               bf16* __restrict__ out2,
                                               float* __restrict__ outf) {
  __shared__ bf16 As[2][128 * 64];
  __shared__ bf16 Bs[2][128 * 64];
  const int bid = blockIdx.x;
  const int mt = bid % 64;
  const int nt = bid / 64;
  const int t = threadIdx.x;
  const int lane = t & 63, w = t >> 6;
  const int wm = w >> 1, wn = w & 1;
  const int l15 = lane & 15, lg = lane >> 4;

  f32x4 acc[4][4] = {};

  const int srow = t >> 3;                        // row within 32-row chunk
  const int skel = ((t & 7) ^ (srow & 7)) * 8;    // pre-swizzled source slot
  const bf16* Ag = A + (size_t)(mt * 128) * KDIM;
  const bf16* Bg = W + (size_t)(nt * 128) * KDIM;
  const int bA = mt >> 3;              // MODE 1: batch of this M-tile
  const int nbase = (mt & 7) * 128;    // MODE 1: n-base of this M-tile

  // A/B global source for K-step st (element offset st*64), chunk c
#define ASRC(st, c)                                                          \
  ((MODE == 0)                                                               \
       ? (Ag + (size_t)((c) * 32 + srow) * KDIM + (st) * 64 + skel)          \
       : (A + (((size_t)(bA * 12 + (st)) * 1024) + nbase + (c) * 32 + srow)  \
              * 64 + skel))
#define BSRC(st, c) (Bg + (size_t)((c) * 32 + srow) * KDIM + (st) * 64 + skel)

  // prologue: stage K-step 0 into buffer 0
#pragma unroll
  for (int c = 0; c < 4; ++c) {
    gload_lds16(ASRC(0, c), (char*)As[0] + c * 4096 + w * 1024);
    gload_lds16(BSRC(0, c), (char*)Bs[0] + c * 4096 + w * 1024);
  }
  __syncthreads();

  const int swz = l15 & 7;   // reader-side swizzle (row&7 == l15&7)

  for (int st = 0; st < KDIM / 64; ++st) {
    const int cur = st & 1;
    if (st < KDIM / 64 - 1) {  // stage next K-step into the other buffer
#pragma unroll
      for (int c = 0; c < 4; ++c) {
        gload_lds16(ASRC(st + 1, c), (char*)As[cur ^ 1] + c * 4096 + w * 1024);
        gload_lds16(BSRC(st + 1, c), (char*)Bs[cur ^ 1] + c * 4096 + w * 1024);
      }
    }
#pragma unroll
    for (int ks = 0; ks < 2; ++ks) {
      bf16x8 af[4], bfr[4];
#pragma unroll
      for (int i = 0; i < 4; ++i)
        af[i] = *(const bf16x8*)(As[cur] + (wm * 64 + i * 16 + l15) * 64 +
                                 ((ks * 4 + lg) ^ swz) * 8);
#pragma unroll
      for (int i = 0; i < 4; ++i)
        bfr[i] = *(const bf16x8*)(Bs[cur] + (wn * 64 + i * 16 + l15) * 64 +
                                  ((ks * 4 + lg) ^ swz) * 8);
#pragma unroll
      for (int i = 0; i < 4; ++i)
#pragma unroll
        for (int j = 0; j < 4; ++j)
          acc[i][j] = MFMA_16x16x32(af[i], bfr[j], acc[i][j]);
    }
    __syncthreads();  // drains vmcnt (next-tile loads done); frees buf[cur]
  }
#undef ASRC
#undef BSRC

  if (MODE == 0) {
    const int which = (nt * 128) / 768;  // 768 = 6*128, tiles never straddle
#pragma unroll
    for (int i = 0; i < 4; ++i)
#pragma unroll
      for (int j = 0; j < 4; ++j)
#pragma unroll
        for (int r = 0; r < 4; ++r) {
          const int m = mt * 128 + wm * 64 + i * 16 + lg * 4 + r;
          const int o = nt * 128 + wn * 64 + j * 16 + l15;
          const int b = m >> 10, n = m & 1023;
          const int f = o - which * 768;
          const int h = f >> 6, hd = f & 63;
          const bf16 bv = (bf16)acc[i][j][r];
          if (which == 0)
            out0[(((size_t)(b * 12 + h)) * 1024 + n) * 64 + hd] = bv;
          else if (which == 1)
            out1[(((size_t)(b * 12 + h)) * 1024 + n) * 64 + hd] = bv;
          else
            out2[(((size_t)(b * 12 + h)) * 64 + hd) * 1024 + n] = bv;
        }
  } else {
#pragma unroll
    for (int i = 0; i < 4; ++i)
#pragma unroll
      for (int j = 0; j < 4; ++j) {
        const int o = nt * 128 + wn * 64 + j * 16 + l15;
        const float bv = bias[o];
#pragma unroll
        for (int r = 0; r < 4; ++r) {
          const int m = mt * 128 + wm * 64 + i * 16 + lg * 4 + r;
          outf[(size_t)m * 768 + o] = acc[i][j][r] + bv;
        }
      }
  }
}

// ---------------------------------------------------------------------------
// k_mean (f32 out): kmean[b,n,hd] = mean_h k[b,h,n,hd]
// ---------------------------------------------------------------------------
__global__ __launch_bounds__(256) void kmean_kernel(const bf16* __restrict__ kbuf,
                                                    float* __restrict__ kmean) {
  const int i = blockIdx.x * 256 + threadIdx.x;
  if (i >= B_ * N_ * HD_) return;
  const int hd = i & 63;
  const int n = (i >> 6) & 1023;
  const int b = i >> 16;
  float s = 0.f;
#pragma unroll
  for (int h = 0; h < 12; ++h)
    s += (float)kbuf[(((size_t)(b * 12 + h)) * 1024 + n) * 64 + hd];
  kmean[i] = s * (1.0f / 12.0f);
}

// ---------------------------------------------------------------------------
// MFMA flash attention (R13-validated). Block = 8 waves (512 thr), each wave
// 2 q-tiles of 16 rows -> 256 q-rows/block; grid = 96 bh x 4 qt. Only FOUR
// blocks stream each bh's K/V -> HBM fetch floor ~111MB independent of the
// workgroup->XCD mapping. KBLK=64, double-buffered LDS K/V, swapped-operand
// QK^T, lane-local softmax, contiguous [b][h][n][64] store.
// ---------------------------------------------------------------------------
__global__ __launch_bounds__(512, 4) void attn_mfma(const bf16* __restrict__ qbuf,
                                                    const bf16* __restrict__ kbuf,
                                                    const bf16* __restrict__ vtbuf,
                                                    const float* __restrict__ biasb,
                                                    bf16* __restrict__ outws) {
  __shared__ bf16 Ks[2][4096];  // [64 rows][8 slots of 8 elems], swizzled
  __shared__ bf16 Vs[2][4096];
  const int id = blockIdx.x;
  const int qt = id & 3;
  const int bh = id >> 2;
  const int b = bh / 12;
  const int t = threadIdx.x, lane = t & 63, w = t >> 6;  // w 0..7
  const int l15 = lane & 15, lg = lane >> 4;
  const int qbase = qt * 256 + w * 16;   // tile0 rows; tile1 = qbase + 128

  const bf16* Q = qbuf + ((size_t)bh * 1024 + qbase) * 64;
  const bf16* Kp = kbuf + (size_t)bh * 65536;
  const bf16* Vt = vtbuf + (size_t)bh * 65536;
  const float* bias = biasb + b * 1024;

  // Q as B-operand: col=l15 (q-row), k-slots lg*8+e = d
  const bf16x8 qb0 = *(const bf16x8*)(Q + l15 * 64 + lg * 8);
  const bf16x8 qb1 = *(const bf16x8*)(Q + l15 * 64 + 32 + lg * 8);
  const bf16x8 qc0 = *(const bf16x8*)(Q + (128 + l15) * 64 + lg * 8);
  const bf16x8 qc1 = *(const bf16x8*)(Q + (128 + l15) * 64 + 32 + lg * 8);

  // staging: thread t fills LDS bytes [t*16, t*16+16) of each 8KB tile.
  // K row srow holds key pi(srow); phys slot (t&7) holds logical slot
  // (t&7)^(srow&7)  (bank swizzle via pre-swizzled source).
  const int srow = t >> 3;                 // 0..63
  const int dsl = (t & 7) ^ (srow & 7);
  const int kkey = 32 * ((srow >> 5) & 1) + 4 * ((srow >> 4) & 1) +
                   8 * ((srow >> 2) & 3) + (srow & 3);
  const bf16* srcK = Kp + kkey * 64 + dsl * 8;
  const bf16* srcV = Vt + (size_t)srow * 1024 + dsl * 8;

  gload_lds16(srcK, (char*)&Ks[0][0] + w * 1024);
  gload_lds16(srcV, (char*)&Vs[0][0] + w * 1024);
  __syncthreads();

  const int bb0 = 8 * lg;        // bias quad base (D-row=lg*4+j)
  const int swz = l15 & 7;

  f32x4 oacc[4] = {}, oacc2[4] = {};
  float m = -1e30f, l = 0.f;
  float m2 = -1e30f, l2 = 0.f;

  for (int kt = 0; kt < 16; ++kt) {
    const int cur = kt & 1;
    const int kb = kt * 64;
    if (kt < 15) {  // stage next tile into the other buffer
      gload_lds16(srcK + (size_t)(kb + 64) * 64, (char*)&Ks[cur ^ 1][0] + w * 1024);
      gload_lds16(srcV + (kb + 64), (char*)&Vs[cur ^ 1][0] + w * 1024);
    }

    const bf16* LK = Ks[cur];
    const bf16* LV = Vs[cur];
    float sv[4][4], sw[4][4];
#pragma unroll
    for (int f = 0; f < 4; ++f) {
      const int cf = 32 * (f >> 1) + 4 * (f & 1);
      const bf16* kj = LK + (f * 16 + l15) * 64;
      const bf16x8 ka0 = *(const bf16x8*)(kj + (lg ^ swz) * 8);
      const bf16x8 ka1 = *(const bf16x8*)(kj + ((lg + 4) ^ swz) * 8);
      f32x4 z = {}, y = {};
      z = MFMA_16x16x32(ka0, qb0, z);
      y = MFMA_16x16x32(ka0, qc0, y);
      z = MFMA_16x16x32(ka1, qb1, z);
      y = MFMA_16x16x32(ka1, qc1, y);
      const float4 bi = *(const float4*)(bias + kb + cf + bb0);
      sv[f][0] = z[0] * 0.125f + bi.x;
      sv[f][1] = z[1] * 0.125f + bi.y;
      sv[f][2] = z[2] * 0.125f + bi.z;
      sv[f][3] = z[3] * 0.125f + bi.w;
      sw[f][0] = y[0] * 0.125f + bi.x;
      sw[f][1] = y[1] * 0.125f + bi.y;
      sw[f][2] = y[2] * 0.125f + bi.z;
      sw[f][3] = y[3] * 0.125f + bi.w;
    }
    // per-tile max over 64 keys: 15 local + 2 shuffles each
    float mx = sv[0][0], mx2 = sw[0][0];
#pragma unroll
    for (int f = 0; f < 4; ++f)
#pragma unroll
      for (int j = 0; j < 4; ++j) {
        mx = fmaxf(mx, sv[f][j]);
        mx2 = fmaxf(mx2, sw[f][j]);
      }
    mx = fmaxf(mx, __shfl_xor(mx, 16, 64));
    mx = fmaxf(mx, __shfl_xor(mx, 32, 64));
    mx2 = fmaxf(mx2, __shfl_xor(mx2, 16, 64));
    mx2 = fmaxf(mx2, __shfl_xor(mx2, 32, 64));
    const float mn = fmaxf(m, mx);
    const float mn2 = fmaxf(m2, mx2);
    const float resc = __expf(m - mn);
    const float resc2 = __expf(m2 - mn2);
    m = mn;
    m2 = mn2;

    float rs = 0.f, rs2 = 0.f;
    bf16x8 pa0, pa1, pa2, pa3;
#pragma unroll
    for (int f = 0; f < 4; ++f)
#pragma unroll
      for (int j = 0; j < 4; ++j) {
        const float p = __expf(sv[f][j] - mn);
        const float p2 = __expf(sw[f][j] - mn2);
        rs += p;
        rs2 += p2;
        const bf16 pb = (bf16)p;
        const bf16 pb2 = (bf16)p2;
        if (f == 0) { pa0[j] = pb; pa2[j] = pb2; }
        else if (f == 1) { pa0[4 + j] = pb; pa2[4 + j] = pb2; }
        else if (f == 2) { pa1[j] = pb; pa3[j] = pb2; }
        else { pa1[4 + j] = pb; pa3[4 + j] = pb2; }
      }
    rs += __shfl_xor(rs, 16, 64);
    rs += __shfl_xor(rs, 32, 64);
    rs2 += __shfl_xor(rs2, 16, 64);
    rs2 += __shfl_xor(rs2, 32, 64);
    l = l * resc + rs;
    l2 = l2 * resc2 + rs2;

#pragma unroll
    for (int df = 0; df < 4; ++df) {
      const bf16* vj = LV + (df * 16 + l15) * 64;
      const bf16x8 va0 = *(const bf16x8*)(vj + (lg ^ swz) * 8);
      const bf16x8 va1 = *(const bf16x8*)(vj + ((lg + 4) ^ swz) * 8);
      f32x4 t4 = oacc[df];
      f32x4 u4 = oacc2[df];
#pragma unroll
      for (int j = 0; j < 4; ++j) {
        t4[j] *= resc;
        u4[j] *= resc2;
      }
      t4 = MFMA_16x16x32(va0, pa0, t4);
      u4 = MFMA_16x16x32(va0, pa2, u4);
      t4 = MFMA_16x16x32(va1, pa1, t4);
      u4 = MFMA_16x16x32(va1, pa3, u4);
      oacc[df] = t4;
      oacc2[df] = u4;
    }
    __syncthreads();  // drains vmcnt (stage t+1 done); frees buf[cur]
  }

  // contiguous store: attnw[b][h][n][64]; tile0 rows qbase.., tile1 +128
  const float inv = 1.0f / l;
  const float inv2 = 1.0f / l2;
  bf16* outp = outws + ((size_t)bh * 1024 + qbase + l15) * 64;
#pragma unroll
  for (int df = 0; df < 4; ++df) {
    bf16x4 ov = {(bf16)(oacc[df][0] * inv), (bf16)(oacc[df][1] * inv),
                 (bf16)(oacc[df][2] * inv), (bf16)(oacc[df][3] * inv)};
    *(bf16x4*)(outp + df * 16 + lg * 4) = ov;
    bf16x4 ov2 = {(bf16)(oacc2[df][0] * inv2), (bf16)(oacc2[df][1] * inv2),
                  (bf16)(oacc2[df][2] * inv2), (bf16)(oacc2[df][3] * inv2)};
    *(bf16x4*)(outp + (size_t)128 * 64 + df * 16 + lg * 4) = ov2;
  }
}

// ---------------------------------------------------------------------------
extern "C" void kernel_launch(void* const* d_in, const int* in_sizes, int n_in,
                              void* d_out, int out_size, void* d_ws, size_t ws_size,
                              hipStream_t stream) {
  const float* x       = (const float*)d_in[0];
  const float* size_in = (const float*)d_in[1];
  const void*  mask    = d_in[2];
  const float* w_qkv   = (const float*)d_in[3];
  const float* w_proj  = (const float*)d_in[4];
  const float* b_proj  = (const float*)d_in[5];
  float* out = (float*)d_out;   // f32 outputs per reference dtype

  if (n_in < 6 ||
      in_sizes[0] != 6291456 || in_sizes[1] != 8192 || in_sizes[2] != 8192 ||
      in_sizes[3] != 1769472 || in_sizes[4] != 589824 || in_sizes[5] != 768)
    return;

  const size_t QS = (size_t)B_ * H_ * N_ * HD_;  // 6291456 elems
  if (ws_size < 55083024) return;

  bf16* xb    = (bf16*)d_ws;       // dead after gemm<0>; reused as attnw
  bf16* qbuf  = xb + QS;
  bf16* kbuf  = qbuf + QS;
  bf16* vtbuf = kbuf + QS;
  bf16* wqb   = vtbuf + QS;        // 1769472 elems
  bf16* wpb   = wqb + 1769472;     // 589824 elems
  float* biasb = (float*)(wpb + 589824);
  int* flags = (int*)(biasb + 8192);
  bf16* attnw = xb;                // [b][h][n][64]

  hipMemsetAsync(flags, 0, 8, stream);
  detect_mask_kernel<<<8, 256, 0, stream>>>((const unsigned*)mask, flags);
  cvt_kernel<<<6144, 256, 0, stream>>>(x, w_qkv, w_proj, size_in, mask, flags,
                                       xb, wqb, wpb, biasb);
  gemm_bt<0><<<64 * 18, 256, 0, stream>>>(xb, wqb, nullptr, qbuf, kbuf, vtbuf, nullptr);
  kmean_kernel<<<2048, 256, 0, stream>>>(kbuf, out + (size_t)B_ * N_ * C_);
  attn_mfma<<<384, 512, 0, stream>>>(qbuf, kbuf, vtbuf, biasb, attnw);
  gemm_bt<1><<<64 * 6, 256, 0, stream>>>(attnw, wpb, b_proj, nullptr, nullptr, nullptr, out);
}